// Round 2
// baseline (646.436 us; speedup 1.0000x reference)
//
#include <hip/hip_runtime.h>

// ---------- types ----------
typedef __attribute__((ext_vector_type(8))) __bf16 bf16x8;   // MFMA A/B operand (4 VGPR)
typedef __attribute__((ext_vector_type(4))) float  f32x4;    // MFMA C/D operand
typedef __attribute__((ext_vector_type(4))) short  short4v;  // 8B packed bf16 store
typedef __attribute__((ext_vector_type(4))) float  float4v;

#define MFMA16(a,b,c) __builtin_amdgcn_mfma_f32_16x16x32_bf16((a),(b),(c),0,0,0)

// fp32 -> bf16 bits, round-to-nearest-even (finite inputs only)
__device__ __forceinline__ short f2bf(float f){
    unsigned int u = __builtin_bit_cast(unsigned int, f);
    u += 0x7fffu + ((u >> 16) & 1u);
    return (short)(u >> 16);
}

typedef __attribute__((address_space(1))) void gvoid;
typedef __attribute__((address_space(3))) void lvoid;
__device__ __forceinline__ void async_copy16(const void* g, void* l){
    // LDS generic pointers carry the LDS offset in the low 32 bits (aperture base
    // has zero low half), so the truncating cast yields the AS(3) offset.
    __builtin_amdgcn_global_load_lds(
        (gvoid*)(unsigned long long)g,
        (lvoid*)(unsigned int)(unsigned long long)l,
        16, 0, 0);
}

// ---------- problem constants ----------
#define BATCH 4
#define SEQ   2048
#define CDIM  1024
#define NH    16
#define HD    64
#define BT    8192          // BATCH*SEQ
#define QSCALE 0.0125f      // 0.1 / sqrt(64)
#define L2E 1.44269504088896340736f

// ---------- 1) fp32 -> bf16 elementwise (x) ----------
__global__ __launch_bounds__(256) void cvt_x(const float* __restrict__ x,
                                             short* __restrict__ xb){
    int idx = blockIdx.x * 256 + threadIdx.x;      // 8 elems / thread, exact cover
    const float* s = x + (size_t)idx * 8;
    float4v a = *(const float4v*)(s);
    float4v b = *(const float4v*)(s + 4);
    short4v lo, hi;
#pragma unroll
    for (int j = 0; j < 4; ++j){ lo[j] = f2bf(a[j]); hi[j] = f2bf(b[j]); }
    short4v* d = (short4v*)(xb + (size_t)idx * 8);
    d[0] = lo; d[1] = hi;
}

// ---------- 2) fp32 W[K][N] -> bf16 Wt[N][K] (transpose-convert) ----------
__global__ __launch_bounds__(256) void wtrans(const float* __restrict__ W,
                                              short* __restrict__ Wt,
                                              int K, int N){
    __shared__ __align__(16) short lds[64 * 80];
    int tid = threadIdx.x;
    int n0 = blockIdx.x * 64, k0 = blockIdx.y * 64;
#pragma unroll
    for (int it = 0; it < 4; ++it){
        int idx = it * 256 + tid;
        int r = idx >> 4, c4 = (idx & 15) << 2;
        float4v w = *(const float4v*)(W + (size_t)(k0 + r) * N + n0 + c4);
        short4v h4;
#pragma unroll
        for (int j = 0; j < 4; ++j) h4[j] = f2bf(w[j]);
        *(short4v*)(&lds[r * 80 + c4]) = h4;
    }
    __syncthreads();
#pragma unroll
    for (int it = 0; it < 2; ++it){
        int idx = it * 256 + tid;
        int nl = idx >> 3, k8 = (idx & 7) << 3;
        short4v o0, o1;
#pragma unroll
        for (int j = 0; j < 4; ++j){
            o0[j] = lds[(k8 + j) * 80 + nl];
            o1[j] = lds[(k8 + 4 + j) * 80 + nl];
        }
        short4v* d = (short4v*)(Wt + (size_t)(n0 + nl) * K + k0 + k8);
        d[0] = o0; d[1] = o1;
    }
}

// ---------- 3) GEMM core: C[M][*] = A[M][1024] * Bt[N][1024]^T ----------
#define BM 128
#define BN 128
#define BK 32
#define KDIM 1024

// QKV GEMM with scatter epilogue into q/k/v [B,H,T,64] (q pre-scaled)
__global__ __launch_bounds__(256) void qkv_gemm(const short* __restrict__ A,
                                                const short* __restrict__ Bt,
                                                const float* __restrict__ bias,
                                                short* __restrict__ q,
                                                short* __restrict__ k,
                                                short* __restrict__ v){
    __shared__ __align__(16) short As[2][BM * BK];
    __shared__ __align__(16) short Bs[2][BM * BK];
    const int tid = threadIdx.x;
    const int bn = blockIdx.x, bm = blockIdx.y;
    const int lane = tid & 63, wid = tid >> 6;
    const int wr = wid >> 1, wc = wid & 1;
    const int li = lane & 15, g = lane >> 4;
    const int arow0 = bm * BM, brow0 = bn * BN;

    f32x4 acc[4][4];
#pragma unroll
    for (int i = 0; i < 4; ++i)
#pragma unroll
        for (int j = 0; j < 4; ++j) acc[i][j] = f32x4{0.f,0.f,0.f,0.f};

    auto stage = [&](int buf, int kt){
        const short* ga = A  + (size_t)arow0 * KDIM + kt * BK;
        const short* gb = Bt + (size_t)brow0 * KDIM + kt * BK;
#pragma unroll
        for (int h = 0; h < 2; ++h){
            int f = h * 256 + tid;
            int row = f >> 2, kc = (f & 3) << 3;
            async_copy16(ga + (size_t)row * KDIM + kc, &As[buf][f << 3]);
            async_copy16(gb + (size_t)row * KDIM + kc, &Bs[buf][f << 3]);
        }
    };

    stage(0, 0);
    __syncthreads();
    int buf = 0;
    const int KT = KDIM / BK;
    for (int kt = 0; kt < KT; ++kt){
        if (kt + 1 < KT) stage(buf ^ 1, kt + 1);
        bf16x8 af[4], bfr[4];
#pragma unroll
        for (int mi = 0; mi < 4; ++mi)
            af[mi] = *(const bf16x8*)(&As[buf][(wr*64 + mi*16 + li) * BK + g*8]);
#pragma unroll
        for (int ni = 0; ni < 4; ++ni)
            bfr[ni] = *(const bf16x8*)(&Bs[buf][(wc*64 + ni*16 + li) * BK + g*8]);
#pragma unroll
        for (int mi = 0; mi < 4; ++mi)
#pragma unroll
            for (int ni = 0; ni < 4; ++ni)
                acc[mi][ni] = MFMA16(af[mi], bfr[ni], acc[mi][ni]);
        __syncthreads();
        buf ^= 1;
    }

    // epilogue: section (q/k/v) and head are uniform per wave
    const int sec = bn >> 3;                    // 0:q 1:k 2:v
    const int h   = ((bn & 7) << 1) | wc;      // head
    short* dst = (sec == 0) ? q : ((sec == 1) ? k : v);
    const float mul = (sec == 0) ? QSCALE : 1.0f;
#pragma unroll
    for (int ni = 0; ni < 4; ++ni){
        int d = ni * 16 + li;                  // 0..63 within head
        float bb = bias[bn * 128 + wc * 64 + d];
#pragma unroll
        for (int mi = 0; mi < 4; ++mi){
#pragma unroll
            for (int r = 0; r < 4; ++r){
                int row = arow0 + wr * 64 + mi * 16 + g * 4 + r;  // global b*T+t
                int b_ = row >> 11, t = row & 2047;
                float val = (acc[mi][ni][r] + bb) * mul;
                dst[(((size_t)(b_ * NH + h)) * SEQ + t) * HD + d] = f2bf(val);
            }
        }
    }
}

// Projection GEMM, fp32 output
__global__ __launch_bounds__(256) void proj_gemm(const short* __restrict__ A,
                                                 const short* __restrict__ Bt,
                                                 const float* __restrict__ bias,
                                                 float* __restrict__ out){
    __shared__ __align__(16) short As[2][BM * BK];
    __shared__ __align__(16) short Bs[2][BM * BK];
    const int tid = threadIdx.x;
    const int bn = blockIdx.x, bm = blockIdx.y;
    const int lane = tid & 63, wid = tid >> 6;
    const int wr = wid >> 1, wc = wid & 1;
    const int li = lane & 15, g = lane >> 4;
    const int arow0 = bm * BM, brow0 = bn * BN;

    f32x4 acc[4][4];
#pragma unroll
    for (int i = 0; i < 4; ++i)
#pragma unroll
        for (int j = 0; j < 4; ++j) acc[i][j] = f32x4{0.f,0.f,0.f,0.f};

    auto stage = [&](int buf, int kt){
        const short* ga = A  + (size_t)arow0 * KDIM + kt * BK;
        const short* gb = Bt + (size_t)brow0 * KDIM + kt * BK;
#pragma unroll
        for (int h = 0; h < 2; ++h){
            int f = h * 256 + tid;
            int row = f >> 2, kc = (f & 3) << 3;
            async_copy16(ga + (size_t)row * KDIM + kc, &As[buf][f << 3]);
            async_copy16(gb + (size_t)row * KDIM + kc, &Bs[buf][f << 3]);
        }
    };

    stage(0, 0);
    __syncthreads();
    int buf = 0;
    const int KT = KDIM / BK;
    for (int kt = 0; kt < KT; ++kt){
        if (kt + 1 < KT) stage(buf ^ 1, kt + 1);
        bf16x8 af[4], bfr[4];
#pragma unroll
        for (int mi = 0; mi < 4; ++mi)
            af[mi] = *(const bf16x8*)(&As[buf][(wr*64 + mi*16 + li) * BK + g*8]);
#pragma unroll
        for (int ni = 0; ni < 4; ++ni)
            bfr[ni] = *(const bf16x8*)(&Bs[buf][(wc*64 + ni*16 + li) * BK + g*8]);
#pragma unroll
        for (int mi = 0; mi < 4; ++mi)
#pragma unroll
            for (int ni = 0; ni < 4; ++ni)
                acc[mi][ni] = MFMA16(af[mi], bfr[ni], acc[mi][ni]);
        __syncthreads();
        buf ^= 1;
    }

#pragma unroll
    for (int ni = 0; ni < 4; ++ni){
        int c = brow0 + wc * 64 + ni * 16 + li;
        float bb = bias[c];
#pragma unroll
        for (int mi = 0; mi < 4; ++mi){
#pragma unroll
            for (int r = 0; r < 4; ++r){
                int row = arow0 + wr * 64 + mi * 16 + g * 4 + r;
                out[(size_t)row * CDIM + c] = acc[mi][ni][r] + bb;
            }
        }
    }
}

// ---------- 4) v [B,H,T,64] -> vt [B,H,64,T] ----------
__global__ __launch_bounds__(256) void vtrans(const short* __restrict__ v,
                                              short* __restrict__ vt){
    __shared__ __align__(16) short lds[64 * 80];
    int tid = threadIdx.x;
    int t0 = blockIdx.x * 64;
    int bh = blockIdx.y;
    const short* src = v + ((size_t)bh * SEQ + t0) * HD;
#pragma unroll
    for (int it = 0; it < 2; ++it){
        int idx = it * 256 + tid;
        int r = idx >> 3, c8 = (idx & 7) << 3;
        *(bf16x8*)(&lds[r * 80 + c8]) = *(const bf16x8*)(src + (size_t)r * HD + c8);
    }
    __syncthreads();
    short* dst = vt + (size_t)bh * HD * SEQ + t0;
#pragma unroll
    for (int it = 0; it < 2; ++it){
        int idx = it * 256 + tid;
        int dl = idx >> 3, t8 = (idx & 7) << 3;
        short4v o0, o1;
#pragma unroll
        for (int j = 0; j < 4; ++j){
            o0[j] = lds[(t8 + j) * 80 + dl];
            o1[j] = lds[(t8 + 4 + j) * 80 + dl];
        }
        short4v* d = (short4v*)(dst + (size_t)dl * SEQ + t8);
        d[0] = o0; d[1] = o1;
    }
}

// ---------- 5) flash attention, swapped-QK^T, y^T = V^T * P^T ----------
// q,k: [B*H, T, 64] bf16 (q pre-scaled); vt: [B*H, 64, T]; y: [B, T, C] bf16
__global__ __launch_bounds__(256) void attn_kernel(const short* __restrict__ q,
                                                   const short* __restrict__ kk,
                                                   const short* __restrict__ vt,
                                                   short* __restrict__ y){
    __shared__ __align__(16) char psm[4 * 2048];   // per-wave [16][64] bf16, swizzled
    const int tid = threadIdx.x;
    const int qt = blockIdx.x;     // 0..31
    const int bh = blockIdx.y;     // 0..63
    const int lane = tid & 63, wid = tid >> 6;
    const int li = lane & 15, g = lane >> 4;
    const int iglob = qt * 64 + wid * 16 + li;     // this lane's q row (col of S^T)

    const short* qp = q + ((size_t)bh * SEQ + iglob) * HD;
    bf16x8 qf0 = *(const bf16x8*)(qp + g * 8);
    bf16x8 qf1 = *(const bf16x8*)(qp + 32 + g * 8);

    char* pbase = psm + wid * 2048 + li * 128;
    const int sw = (li & 7) << 4;

    f32x4 acc[4];
#pragma unroll
    for (int df = 0; df < 4; ++df) acc[df] = f32x4{0.f,0.f,0.f,0.f};
    float m = -3e38f, l = 0.f;

    const short* kbp = kk + (size_t)bh * SEQ * HD;
    const short* vbp = vt + (size_t)bh * HD * SEQ;

    for (int kt = 0; kt <= qt; ++kt){
        const int kb = kt * 64;
        f32x4 st[4];
#pragma unroll
        for (int kf = 0; kf < 4; ++kf) st[kf] = f32x4{0.f,0.f,0.f,0.f};
#pragma unroll
        for (int kf = 0; kf < 4; ++kf){
            const short* kr = kbp + ((size_t)(kb + kf * 16 + li)) * HD + g * 8;
            bf16x8 k0 = *(const bf16x8*)(kr);
            bf16x8 k1 = *(const bf16x8*)(kr + 32);
            st[kf] = MFMA16(k0, qf0, st[kf]);
            st[kf] = MFMA16(k1, qf1, st[kf]);
        }
        if (kt == qt){
#pragma unroll
            for (int kf = 0; kf < 4; ++kf)
#pragma unroll
                for (int r = 0; r < 4; ++r)
                    if (kb + kf * 16 + g * 4 + r > iglob) st[kf][r] = -3e38f;
        }
        // softmax (per q-row = per lane after g-reduction)
        float pm = -3e38f;
#pragma unroll
        for (int kf = 0; kf < 4; ++kf)
#pragma unroll
            for (int r = 0; r < 4; ++r) pm = fmaxf(pm, st[kf][r]);
        pm = fmaxf(pm, __shfl_xor(pm, 16, 64));
        pm = fmaxf(pm, __shfl_xor(pm, 32, 64));
        float mnew = fmaxf(m, pm);
        float alpha = __builtin_amdgcn_exp2f((m - mnew) * L2E);
        float rs = 0.f;
#pragma unroll
        for (int kf = 0; kf < 4; ++kf){
            short4v pk;
#pragma unroll
            for (int r = 0; r < 4; ++r){
                float p = __builtin_amdgcn_exp2f((st[kf][r] - mnew) * L2E);
                rs += p;
                pk[r] = f2bf(p);
            }
            *(short4v*)(pbase + (((kf << 5) + (g << 3)) ^ sw)) = pk;
        }
        rs += __shfl_xor(rs, 16, 64);
        rs += __shfl_xor(rs, 32, 64);
        l = l * alpha + rs;
        m = mnew;
#pragma unroll
        for (int df = 0; df < 4; ++df) acc[df] *= alpha;

        bf16x8 pb0 = *(const bf16x8*)(pbase + (((g << 4)) ^ sw));
        bf16x8 pb1 = *(const bf16x8*)(pbase + ((64 + (g << 4)) ^ sw));
#pragma unroll
        for (int df = 0; df < 4; ++df){
            const short* vr = vbp + ((size_t)(df * 16 + li)) * SEQ + kb + g * 8;
            bf16x8 v0 = *(const bf16x8*)(vr);
            bf16x8 v1 = *(const bf16x8*)(vr + 32);
            acc[df] = MFMA16(v0, pb0, acc[df]);
            acc[df] = MFMA16(v1, pb1, acc[df]);
        }
    }

    float rl = 1.f / l;
    const int b_ = bh >> 4, h = bh & 15;
    short* yp = y + ((size_t)(b_ * SEQ + iglob)) * CDIM + h * HD;
#pragma unroll
    for (int df = 0; df < 4; ++df){
        short4v o;
#pragma unroll
        for (int r = 0; r < 4; ++r) o[r] = f2bf(acc[df][r] * rl);
        *(short4v*)(yp + df * 16 + g * 4) = o;
    }
}

// ---------- launch ----------
extern "C" void kernel_launch(void* const* d_in, const int* in_sizes, int n_in,
                              void* d_out, int out_size, void* d_ws, size_t ws_size,
                              hipStream_t stream){
    const float* x      = (const float*)d_in[0];
    const float* W_attn = (const float*)d_in[1];
    const float* b_attn = (const float*)d_in[2];
    const float* W_proj = (const float*)d_in[3];
    const float* b_proj = (const float*)d_in[4];
    float* out = (float*)d_out;

    // Workspace layout (92,274,688 B total). y aliases xb: xb is dead after
    // qkv_gemm; y is first written by attn_kernel, which runs later.
    //   [0,  2MB)   Wtp    bf16 W_proj^T  [1024][1024]
    //   [2, 18MB)   q      bf16 [B,H,T,64] (pre-scaled)
    //   [18,34MB)   k      bf16 [B,H,T,64]
    //   [34,50MB)   v      bf16 [B,H,T,64]
    //   [50,66MB)   vt     bf16 [B,H,64,T]
    //   [66,82MB)   xb/y   bf16 x [B*T,C]  -> reused as y [B,T,C]
    //   [82,88MB)   Wta    bf16 W_attn^T  [3072][1024]
    if (ws_size < (size_t)92274688) return;  // avoid OOB writes -> clean failure

    char* ws = (char*)d_ws;
    short* Wtp = (short*)(ws);
    short* q   = (short*)(ws + 2097152);
    short* kk  = (short*)(ws + 18874368);
    short* v   = (short*)(ws + 35651584);
    short* vt  = (short*)(ws + 52428800);
    short* xb  = (short*)(ws + 69206016);
    short* y   = xb;
    short* Wta = (short*)(ws + 85983232);

    cvt_x <<<4096, 256, 0, stream>>>(x, xb);
    wtrans<<<dim3(48, 16), 256, 0, stream>>>(W_attn, Wta, 1024, 3072);
    wtrans<<<dim3(16, 16), 256, 0, stream>>>(W_proj, Wtp, 1024, 1024);
    qkv_gemm<<<dim3(24, 64), 256, 0, stream>>>(xb, Wta, b_attn, q, kk, v);
    vtrans<<<dim3(32, 64), 256, 0, stream>>>(v, vt);
    attn_kernel<<<dim3(32, 64), 256, 0, stream>>>(q, kk, vt, y);
    proj_gemm<<<dim3(8, 64), 256, 0, stream>>>(y, Wtp, b_proj, out);
}

// Round 6
// 326.574 us; speedup vs baseline: 1.9794x; 1.9794x over previous
//
#include <hip/hip_runtime.h>

// ---------- types ----------
typedef __attribute__((ext_vector_type(8))) __bf16 bf16x8;   // MFMA A/B operand (4 VGPR)
typedef __attribute__((ext_vector_type(4))) float  f32x4;    // MFMA C/D operand
typedef __attribute__((ext_vector_type(4))) short  short4v;  // 8B packed bf16 store
typedef __attribute__((ext_vector_type(4))) float  float4v;

#define MFMA16(a,b,c) __builtin_amdgcn_mfma_f32_16x16x32_bf16((a),(b),(c),0,0,0)

// fp32 -> bf16 bits, round-to-nearest-even (finite inputs only)
__device__ __forceinline__ short f2bf(float f){
    unsigned int u = __builtin_bit_cast(unsigned int, f);
    u += 0x7fffu + ((u >> 16) & 1u);
    return (short)(u >> 16);
}

typedef __attribute__((address_space(1))) void gvoid;
typedef __attribute__((address_space(3))) void lvoid;
__device__ __forceinline__ void async_copy16(const void* g, void* l){
    __builtin_amdgcn_global_load_lds(
        (gvoid*)(unsigned long long)g,
        (lvoid*)(unsigned int)(unsigned long long)l,
        16, 0, 0);
}

// ---------- problem constants ----------
#define BATCH 4
#define SEQ   2048
#define CDIM  1024
#define NH    16
#define HD    64
#define BT    8192          // BATCH*SEQ
#define QSCALE 0.0125f      // 0.1 / sqrt(64)
#define L2E 1.44269504088896340736f

// ---------- 1) fp32 -> bf16 elementwise (x) ----------
__global__ __launch_bounds__(256) void cvt_x(const float* __restrict__ x,
                                             short* __restrict__ xb){
    int idx = blockIdx.x * 256 + threadIdx.x;      // 8 elems / thread, exact cover
    const float* s = x + (size_t)idx * 8;
    float4v a = *(const float4v*)(s);
    float4v b = *(const float4v*)(s + 4);
    short4v lo, hi;
#pragma unroll
    for (int j = 0; j < 4; ++j){ lo[j] = f2bf(a[j]); hi[j] = f2bf(b[j]); }
    short4v* d = (short4v*)(xb + (size_t)idx * 8);
    d[0] = lo; d[1] = hi;
}

// ---------- 2) fp32 W[K][N] -> bf16 Wt[N][K] (transpose-convert) ----------
__global__ __launch_bounds__(256) void wtrans(const float* __restrict__ W,
                                              short* __restrict__ Wt,
                                              int K, int N){
    __shared__ __align__(16) short lds[64 * 80];
    int tid = threadIdx.x;
    int n0 = blockIdx.x * 64, k0 = blockIdx.y * 64;
#pragma unroll
    for (int it = 0; it < 4; ++it){
        int idx = it * 256 + tid;
        int r = idx >> 4, c4 = (idx & 15) << 2;
        float4v w = *(const float4v*)(W + (size_t)(k0 + r) * N + n0 + c4);
        short4v h4;
#pragma unroll
        for (int j = 0; j < 4; ++j) h4[j] = f2bf(w[j]);
        *(short4v*)(&lds[r * 80 + c4]) = h4;
    }
    __syncthreads();
#pragma unroll
    for (int it = 0; it < 2; ++it){
        int idx = it * 256 + tid;
        int nl = idx >> 3, k8 = (idx & 7) << 3;
        short4v o0, o1;
#pragma unroll
        for (int j = 0; j < 4; ++j){
            o0[j] = lds[(k8 + j) * 80 + nl];
            o1[j] = lds[(k8 + 4 + j) * 80 + nl];
        }
        short4v* d = (short4v*)(Wt + (size_t)(n0 + nl) * K + k0 + k8);
        d[0] = o0; d[1] = o1;
    }
}

// ---------- 3) GEMM core: C[M][*] = A[M][1024] * Bt[N][1024]^T ----------
#define BM 128
#define BN 128
#define BK 32
#define KDIM 1024

// QKV GEMM with scatter epilogue into q/k/v [B,H,T,64] (q pre-scaled)
__global__ __launch_bounds__(256) void qkv_gemm(const short* __restrict__ A,
                                                const short* __restrict__ Bt,
                                                const float* __restrict__ bias,
                                                short* __restrict__ q,
                                                short* __restrict__ k,
                                                short* __restrict__ v){
    __shared__ __align__(16) short As[2][BM * BK];
    __shared__ __align__(16) short Bs[2][BM * BK];
    const int tid = threadIdx.x;
    const int bn = blockIdx.x, bm = blockIdx.y;
    const int lane = tid & 63, wid = tid >> 6;
    const int wr = wid >> 1, wc = wid & 1;
    const int li = lane & 15, g = lane >> 4;
    const int arow0 = bm * BM, brow0 = bn * BN;

    f32x4 acc[4][4];
#pragma unroll
    for (int i = 0; i < 4; ++i)
#pragma unroll
        for (int j = 0; j < 4; ++j) acc[i][j] = f32x4{0.f,0.f,0.f,0.f};

    auto stage = [&](int buf, int kt){
        const short* ga = A  + (size_t)arow0 * KDIM + kt * BK;
        const short* gb = Bt + (size_t)brow0 * KDIM + kt * BK;
#pragma unroll
        for (int h = 0; h < 2; ++h){
            int f = h * 256 + tid;
            int row = f >> 2, kc = (f & 3) << 3;
            async_copy16(ga + (size_t)row * KDIM + kc, &As[buf][f << 3]);
            async_copy16(gb + (size_t)row * KDIM + kc, &Bs[buf][f << 3]);
        }
    };

    stage(0, 0);
    __syncthreads();
    int buf = 0;
    const int KT = KDIM / BK;
    for (int kt = 0; kt < KT; ++kt){
        if (kt + 1 < KT) stage(buf ^ 1, kt + 1);
        bf16x8 af[4], bfr[4];
#pragma unroll
        for (int mi = 0; mi < 4; ++mi)
            af[mi] = *(const bf16x8*)(&As[buf][(wr*64 + mi*16 + li) * BK + g*8]);
#pragma unroll
        for (int ni = 0; ni < 4; ++ni)
            bfr[ni] = *(const bf16x8*)(&Bs[buf][(wc*64 + ni*16 + li) * BK + g*8]);
#pragma unroll
        for (int mi = 0; mi < 4; ++mi)
#pragma unroll
            for (int ni = 0; ni < 4; ++ni)
                acc[mi][ni] = MFMA16(af[mi], bfr[ni], acc[mi][ni]);
        __syncthreads();
        buf ^= 1;
    }

    // epilogue: section (q/k/v) and head are uniform per wave
    const int sec = bn >> 3;                    // 0:q 1:k 2:v
    const int h   = ((bn & 7) << 1) | wc;      // head
    short* dst = (sec == 0) ? q : ((sec == 1) ? k : v);
    const float mul = (sec == 0) ? QSCALE : 1.0f;
#pragma unroll
    for (int ni = 0; ni < 4; ++ni){
        int d = ni * 16 + li;                  // 0..63 within head
        float bb = bias[bn * 128 + wc * 64 + d];
#pragma unroll
        for (int mi = 0; mi < 4; ++mi){
#pragma unroll
            for (int r = 0; r < 4; ++r){
                int row = arow0 + wr * 64 + mi * 16 + g * 4 + r;  // global b*T+t
                int b_ = row >> 11, t = row & 2047;
                float val = (acc[mi][ni][r] + bb) * mul;
                dst[(((size_t)(b_ * NH + h)) * SEQ + t) * HD + d] = f2bf(val);
            }
        }
    }
}

// Projection GEMM, fp32 output
__global__ __launch_bounds__(256) void proj_gemm(const short* __restrict__ A,
                                                 const short* __restrict__ Bt,
                                                 const float* __restrict__ bias,
                                                 float* __restrict__ out){
    __shared__ __align__(16) short As[2][BM * BK];
    __shared__ __align__(16) short Bs[2][BM * BK];
    const int tid = threadIdx.x;
    const int bn = blockIdx.x, bm = blockIdx.y;
    const int lane = tid & 63, wid = tid >> 6;
    const int wr = wid >> 1, wc = wid & 1;
    const int li = lane & 15, g = lane >> 4;
    const int arow0 = bm * BM, brow0 = bn * BN;

    f32x4 acc[4][4];
#pragma unroll
    for (int i = 0; i < 4; ++i)
#pragma unroll
        for (int j = 0; j < 4; ++j) acc[i][j] = f32x4{0.f,0.f,0.f,0.f};

    auto stage = [&](int buf, int kt){
        const short* ga = A  + (size_t)arow0 * KDIM + kt * BK;
        const short* gb = Bt + (size_t)brow0 * KDIM + kt * BK;
#pragma unroll
        for (int h = 0; h < 2; ++h){
            int f = h * 256 + tid;
            int row = f >> 2, kc = (f & 3) << 3;
            async_copy16(ga + (size_t)row * KDIM + kc, &As[buf][f << 3]);
            async_copy16(gb + (size_t)row * KDIM + kc, &Bs[buf][f << 3]);
        }
    };

    stage(0, 0);
    __syncthreads();
    int buf = 0;
    const int KT = KDIM / BK;
    for (int kt = 0; kt < KT; ++kt){
        if (kt + 1 < KT) stage(buf ^ 1, kt + 1);
        bf16x8 af[4], bfr[4];
#pragma unroll
        for (int mi = 0; mi < 4; ++mi)
            af[mi] = *(const bf16x8*)(&As[buf][(wr*64 + mi*16 + li) * BK + g*8]);
#pragma unroll
        for (int ni = 0; ni < 4; ++ni)
            bfr[ni] = *(const bf16x8*)(&Bs[buf][(wc*64 + ni*16 + li) * BK + g*8]);
#pragma unroll
        for (int mi = 0; mi < 4; ++mi)
#pragma unroll
            for (int ni = 0; ni < 4; ++ni)
                acc[mi][ni] = MFMA16(af[mi], bfr[ni], acc[mi][ni]);
        __syncthreads();
        buf ^= 1;
    }

#pragma unroll
    for (int ni = 0; ni < 4; ++ni){
        int c = brow0 + wc * 64 + ni * 16 + li;
        float bb = bias[c];
#pragma unroll
        for (int mi = 0; mi < 4; ++mi){
#pragma unroll
            for (int r = 0; r < 4; ++r){
                int row = arow0 + wr * 64 + mi * 16 + g * 4 + r;
                out[(size_t)row * CDIM + c] = acc[mi][ni][r] + bb;
            }
        }
    }
}

// ---------- 4) v [B,H,T,64] -> vt [B,H,64,T] ----------
__global__ __launch_bounds__(256) void vtrans(const short* __restrict__ v,
                                              short* __restrict__ vt){
    __shared__ __align__(16) short lds[64 * 80];
    int tid = threadIdx.x;
    int t0 = blockIdx.x * 64;
    int bh = blockIdx.y;
    const short* src = v + ((size_t)bh * SEQ + t0) * HD;
#pragma unroll
    for (int it = 0; it < 2; ++it){
        int idx = it * 256 + tid;
        int r = idx >> 3, c8 = (idx & 7) << 3;
        *(bf16x8*)(&lds[r * 80 + c8]) = *(const bf16x8*)(src + (size_t)r * HD + c8);
    }
    __syncthreads();
    short* dst = vt + (size_t)bh * HD * SEQ + t0;
#pragma unroll
    for (int it = 0; it < 2; ++it){
        int idx = it * 256 + tid;
        int dl = idx >> 3, t8 = (idx & 7) << 3;
        short4v o0, o1;
#pragma unroll
        for (int j = 0; j < 4; ++j){
            o0[j] = lds[(t8 + j) * 80 + dl];
            o1[j] = lds[(t8 + 4 + j) * 80 + dl];
        }
        short4v* d = (short4v*)(dst + (size_t)dl * SEQ + t8);
        d[0] = o0; d[1] = o1;
    }
}

// ---------- 5) flash attention, swapped-QK^T, LDS-staged K/V double buffer ----
// q,k: [B*H, T, 64] bf16 (q pre-scaled); vt: [B*H, 64, T]; y: [B, T, C] bf16
// Block = 4 waves, one 64-row q-tile. K/V tiles staged cooperatively into LDS
// (global_load_lds, XOR-swizzled source). 2-phase schedule, ONE barrier/tile:
//   prologue: stage(0); vmcnt(0); barrier
//   loop:     stage(next); compute current; vmcnt(0); barrier
// The end-of-tile vmcnt(0)+barrier (a) completes next tile's loads (hidden
// under compute), (b) guarantees all waves done reading buf before overwrite.
// LDS tile layout: 64 rows x 128B; lds[row][seg] holds global seg (seg ^ (row&7)).
__global__ __launch_bounds__(256) void attn_kernel(const short* __restrict__ q,
                                                   const short* __restrict__ kk,
                                                   const short* __restrict__ vt,
                                                   short* __restrict__ y){
    __shared__ __align__(16) char kvs[2][2][8192];   // [buf][K=0/V=1][64*128B]
    __shared__ __align__(16) char psm[4 * 2048];     // per-wave [16][64] bf16, swizzled
    const int tid = threadIdx.x;
    const int qt = 31 - blockIdx.x;  // longest blocks dispatch first
    const int bh = blockIdx.y;       // 0..63
    const int lane = tid & 63, wid = tid >> 6;
    const int li = lane & 15, g = lane >> 4;
    const int iglob = qt * 64 + wid * 16 + li;       // this lane's q row

    const short* qp = q + ((size_t)bh * SEQ + iglob) * HD;
    bf16x8 qf0 = *(const bf16x8*)(qp + g * 8);
    bf16x8 qf1 = *(const bf16x8*)(qp + 32 + g * 8);

    char* pbase = psm + wid * 2048 + li * 128;
    const int sw = (li & 7) << 4;

    f32x4 acc[4];
#pragma unroll
    for (int df = 0; df < 4; ++df) acc[df] = f32x4{0.f,0.f,0.f,0.f};
    float m = -3e38f, l = 0.f;

    const short* kbp = kk + (size_t)bh * SEQ * HD;
    const short* vbp = vt + (size_t)bh * HD * SEQ;

    // staging: 512 16B-chunks per tile; chunk c -> row r=c>>3, lds seg s=c&7,
    // global seg s^(r&7). Wave w call j covers chunks [(w*2+j)*64, +64).
    const int c0 = (wid * 2) * 64 + lane;        // chunk for j=0
    const int r0 = c0 >> 3, sg0 = (c0 & 7) ^ (r0 & 7);
    const int c1 = c0 + 64;                      // chunk for j=1
    const int r1 = c1 >> 3, sg1 = (c1 & 7) ^ (r1 & 7);

    auto stage = [&](int b, int kt2){
        const int kb2 = kt2 * 64;
        const short* kg = kbp + (size_t)kb2 * HD;
        const short* vg = vbp + kb2;
        char* kd = kvs[b][0];
        char* vd = kvs[b][1];
        async_copy16(kg + r0 * HD + sg0 * 8, kd + c0 * 16);
        async_copy16(kg + r1 * HD + sg1 * 8, kd + c1 * 16);
        async_copy16(vg + (size_t)r0 * SEQ + sg0 * 8, vd + c0 * 16);
        async_copy16(vg + (size_t)r1 * SEQ + sg1 * 8, vd + c1 * 16);
    };

    stage(0, 0);
    asm volatile("s_waitcnt vmcnt(0)" ::: "memory");
    __builtin_amdgcn_s_barrier();
    int buf = 0;
    for (int kt = 0; kt <= qt; ++kt){
        const int kb = kt * 64;
        if (kt < qt) stage(buf ^ 1, kt + 1);

        const char* Kb = kvs[buf][0];
        const char* Vb = kvs[buf][1];

        f32x4 st[4];
#pragma unroll
        for (int kf = 0; kf < 4; ++kf) st[kf] = f32x4{0.f,0.f,0.f,0.f};
#pragma unroll
        for (int kf = 0; kf < 4; ++kf){
            int r = kf * 16 + li;
            bf16x8 k0 = *(const bf16x8*)(Kb + r * 128 + ((g ^ (r & 7)) << 4));
            bf16x8 k1 = *(const bf16x8*)(Kb + r * 128 + (((g + 4) ^ (r & 7)) << 4));
            st[kf] = MFMA16(k0, qf0, st[kf]);
            st[kf] = MFMA16(k1, qf1, st[kf]);
        }
        if (kt == qt){
#pragma unroll
            for (int kf = 0; kf < 4; ++kf)
#pragma unroll
                for (int r = 0; r < 4; ++r)
                    if (kb + kf * 16 + g * 4 + r > iglob) st[kf][r] = -3e38f;
        }
        // softmax (per q-row = per lane after g-reduction)
        float pm = -3e38f;
#pragma unroll
        for (int kf = 0; kf < 4; ++kf)
#pragma unroll
            for (int r = 0; r < 4; ++r) pm = fmaxf(pm, st[kf][r]);
        pm = fmaxf(pm, __shfl_xor(pm, 16, 64));
        pm = fmaxf(pm, __shfl_xor(pm, 32, 64));
        float mnew = fmaxf(m, pm);
        float alpha = __builtin_amdgcn_exp2f((m - mnew) * L2E);
        float rs = 0.f;
#pragma unroll
        for (int kf = 0; kf < 4; ++kf){
            short4v pk;
#pragma unroll
            for (int r = 0; r < 4; ++r){
                float p = __builtin_amdgcn_exp2f((st[kf][r] - mnew) * L2E);
                rs += p;
                pk[r] = f2bf(p);
            }
            *(short4v*)(pbase + (((kf << 5) + (g << 3)) ^ sw)) = pk;
        }
        rs += __shfl_xor(rs, 16, 64);
        rs += __shfl_xor(rs, 32, 64);
        l = l * alpha + rs;
        m = mnew;
#pragma unroll
        for (int df = 0; df < 4; ++df) acc[df] *= alpha;

        bf16x8 pb0 = *(const bf16x8*)(pbase + (((g << 4)) ^ sw));
        bf16x8 pb1 = *(const bf16x8*)(pbase + ((64 + (g << 4)) ^ sw));
#pragma unroll
        for (int df = 0; df < 4; ++df){
            int d = df * 16 + li;
            bf16x8 v0 = *(const bf16x8*)(Vb + d * 128 + ((g ^ (d & 7)) << 4));
            bf16x8 v1 = *(const bf16x8*)(Vb + d * 128 + (((g + 4) ^ (d & 7)) << 4));
            acc[df] = MFMA16(v0, pb0, acc[df]);
            acc[df] = MFMA16(v1, pb1, acc[df]);
        }

        asm volatile("s_waitcnt vmcnt(0)" ::: "memory");  // next tile resident
        __builtin_amdgcn_s_barrier();                     // all waves done w/ buf
        buf ^= 1;
    }

    float rl = 1.f / l;
    const int b_ = bh >> 4, h = bh & 15;
    short* yp = y + ((size_t)(b_ * SEQ + iglob)) * CDIM + h * HD;
#pragma unroll
    for (int df = 0; df < 4; ++df){
        short4v o;
#pragma unroll
        for (int r = 0; r < 4; ++r) o[r] = f2bf(acc[df][r] * rl);
        *(short4v*)(yp + df * 16 + g * 4) = o;
    }
}

// ---------- launch ----------
extern "C" void kernel_launch(void* const* d_in, const int* in_sizes, int n_in,
                              void* d_out, int out_size, void* d_ws, size_t ws_size,
                              hipStream_t stream){
    const float* x      = (const float*)d_in[0];
    const float* W_attn = (const float*)d_in[1];
    const float* b_attn = (const float*)d_in[2];
    const float* W_proj = (const float*)d_in[3];
    const float* b_proj = (const float*)d_in[4];
    float* out = (float*)d_out;

    // Workspace layout (92,274,688 B total). y aliases xb (xb dead after qkv_gemm).
    if (ws_size < (size_t)92274688) return;  // avoid OOB writes -> clean failure

    char* ws = (char*)d_ws;
    short* Wtp = (short*)(ws);
    short* q   = (short*)(ws + 2097152);
    short* kk  = (short*)(ws + 18874368);
    short* v   = (short*)(ws + 35651584);
    short* vt  = (short*)(ws + 52428800);
    short* xb  = (short*)(ws + 69206016);
    short* y   = xb;
    short* Wta = (short*)(ws + 85983232);

    cvt_x <<<4096, 256, 0, stream>>>(x, xb);
    wtrans<<<dim3(48, 16), 256, 0, stream>>>(W_attn, Wta, 1024, 3072);
    wtrans<<<dim3(16, 16), 256, 0, stream>>>(W_proj, Wtp, 1024, 1024);
    qkv_gemm<<<dim3(24, 64), 256, 0, stream>>>(xb, Wta, b_attn, q, kk, v);
    vtrans<<<dim3(32, 64), 256, 0, stream>>>(v, vt);
    attn_kernel<<<dim3(32, 64), 256, 0, stream>>>(q, kk, vt, y);
    proj_gemm<<<dim3(8, 64), 256, 0, stream>>>(y, Wtp, b_proj, out);
}

// Round 8
// 325.265 us; speedup vs baseline: 1.9874x; 1.0040x over previous
//
#include <hip/hip_runtime.h>

// ---------- types ----------
typedef __attribute__((ext_vector_type(8))) __bf16 bf16x8;   // MFMA A/B operand (4 VGPR)
typedef __attribute__((ext_vector_type(4))) float  f32x4;    // MFMA C/D operand
typedef __attribute__((ext_vector_type(4))) short  short4v;  // 8B packed bf16 store
typedef __attribute__((ext_vector_type(4))) float  float4v;
typedef __attribute__((ext_vector_type(2))) unsigned int uint2v;

#define MFMA16(a,b,c) __builtin_amdgcn_mfma_f32_16x16x32_bf16((a),(b),(c),0,0,0)

// fp32 -> bf16 bits, round-to-nearest-even (finite inputs only)
__device__ __forceinline__ short f2bf(float f){
    unsigned int u = __builtin_bit_cast(unsigned int, f);
    u += 0x7fffu + ((u >> 16) & 1u);
    return (short)(u >> 16);
}

// pack two f32 -> one dword of 2 bf16 (RNE), single HW instruction
__device__ __forceinline__ unsigned int cvtpk(float a, float b){
    unsigned int w;
    asm("v_cvt_pk_bf16_f32 %0, %1, %2" : "=v"(w) : "v"(a), "v"(b));
    return w;
}

typedef __attribute__((address_space(1))) void gvoid;
typedef __attribute__((address_space(3))) void lvoid;
__device__ __forceinline__ void async_copy16(const void* g, void* l){
    __builtin_amdgcn_global_load_lds(
        (gvoid*)(unsigned long long)g,
        (lvoid*)(unsigned int)(unsigned long long)l,
        16, 0, 0);
}

// ---------- problem constants ----------
#define BATCH 4
#define SEQ   2048
#define CDIM  1024
#define NH    16
#define HD    64
#define BT    8192          // BATCH*SEQ
#define QSCALE 0.0125f      // 0.1 / sqrt(64)
#define L2E 1.44269504088896340736f
#define DEFER_THR 8.0f      // skip O/l rescale while pm - m <= THR (P <= e^8)

// ---------- 1) fp32 -> bf16 elementwise (x) ----------
__global__ __launch_bounds__(256) void cvt_x(const float* __restrict__ x,
                                             short* __restrict__ xb){
    int idx = blockIdx.x * 256 + threadIdx.x;      // 8 elems / thread, exact cover
    const float* s = x + (size_t)idx * 8;
    float4v a = *(const float4v*)(s);
    float4v b = *(const float4v*)(s + 4);
    short4v lo, hi;
#pragma unroll
    for (int j = 0; j < 4; ++j){ lo[j] = f2bf(a[j]); hi[j] = f2bf(b[j]); }
    short4v* d = (short4v*)(xb + (size_t)idx * 8);
    d[0] = lo; d[1] = hi;
}

// ---------- 2) fp32 W[K][N] -> bf16 Wt[N][K] (transpose-convert) ----------
__global__ __launch_bounds__(256) void wtrans(const float* __restrict__ W,
                                              short* __restrict__ Wt,
                                              int K, int N){
    __shared__ __align__(16) short lds[64 * 80];
    int tid = threadIdx.x;
    int n0 = blockIdx.x * 64, k0 = blockIdx.y * 64;
#pragma unroll
    for (int it = 0; it < 4; ++it){
        int idx = it * 256 + tid;
        int r = idx >> 4, c4 = (idx & 15) << 2;
        float4v w = *(const float4v*)(W + (size_t)(k0 + r) * N + n0 + c4);
        short4v h4;
#pragma unroll
        for (int j = 0; j < 4; ++j) h4[j] = f2bf(w[j]);
        *(short4v*)(&lds[r * 80 + c4]) = h4;
    }
    __syncthreads();
#pragma unroll
    for (int it = 0; it < 2; ++it){
        int idx = it * 256 + tid;
        int nl = idx >> 3, k8 = (idx & 7) << 3;
        short4v o0, o1;
#pragma unroll
        for (int j = 0; j < 4; ++j){
            o0[j] = lds[(k8 + j) * 80 + nl];
            o1[j] = lds[(k8 + 4 + j) * 80 + nl];
        }
        short4v* d = (short4v*)(Wt + (size_t)(n0 + nl) * K + k0 + k8);
        d[0] = o0; d[1] = o1;
    }
}

// ---------- 3) GEMM core: C[M][*] = A[M][1024] * Bt[N][1024]^T ----------
#define BM 128
#define BN 128
#define BK 32
#define KDIM 1024

// QKV GEMM with scatter epilogue into q/k/v [B,H,T,64] (q pre-scaled)
__global__ __launch_bounds__(256) void qkv_gemm(const short* __restrict__ A,
                                                const short* __restrict__ Bt,
                                                const float* __restrict__ bias,
                                                short* __restrict__ q,
                                                short* __restrict__ k,
                                                short* __restrict__ v){
    __shared__ __align__(16) short As[2][BM * BK];
    __shared__ __align__(16) short Bs[2][BM * BK];
    const int tid = threadIdx.x;
    const int bn = blockIdx.x, bm = blockIdx.y;
    const int lane = tid & 63, wid = tid >> 6;
    const int wr = wid >> 1, wc = wid & 1;
    const int li = lane & 15, g = lane >> 4;
    const int arow0 = bm * BM, brow0 = bn * BN;

    f32x4 acc[4][4];
#pragma unroll
    for (int i = 0; i < 4; ++i)
#pragma unroll
        for (int j = 0; j < 4; ++j) acc[i][j] = f32x4{0.f,0.f,0.f,0.f};

    auto stage = [&](int buf, int kt){
        const short* ga = A  + (size_t)arow0 * KDIM + kt * BK;
        const short* gb = Bt + (size_t)brow0 * KDIM + kt * BK;
#pragma unroll
        for (int h = 0; h < 2; ++h){
            int f = h * 256 + tid;
            int row = f >> 2, kc = (f & 3) << 3;
            async_copy16(ga + (size_t)row * KDIM + kc, &As[buf][f << 3]);
            async_copy16(gb + (size_t)row * KDIM + kc, &Bs[buf][f << 3]);
        }
    };

    stage(0, 0);
    __syncthreads();
    int buf = 0;
    const int KT = KDIM / BK;
    for (int kt = 0; kt < KT; ++kt){
        if (kt + 1 < KT) stage(buf ^ 1, kt + 1);
        bf16x8 af[4], bfr[4];
#pragma unroll
        for (int mi = 0; mi < 4; ++mi)
            af[mi] = *(const bf16x8*)(&As[buf][(wr*64 + mi*16 + li) * BK + g*8]);
#pragma unroll
        for (int ni = 0; ni < 4; ++ni)
            bfr[ni] = *(const bf16x8*)(&Bs[buf][(wc*64 + ni*16 + li) * BK + g*8]);
#pragma unroll
        for (int mi = 0; mi < 4; ++mi)
#pragma unroll
            for (int ni = 0; ni < 4; ++ni)
                acc[mi][ni] = MFMA16(af[mi], bfr[ni], acc[mi][ni]);
        __syncthreads();
        buf ^= 1;
    }

    // epilogue: section (q/k/v) and head are uniform per wave
    const int sec = bn >> 3;                    // 0:q 1:k 2:v
    const int h   = ((bn & 7) << 1) | wc;      // head
    short* dst = (sec == 0) ? q : ((sec == 1) ? k : v);
    const float mul = (sec == 0) ? QSCALE : 1.0f;
#pragma unroll
    for (int ni = 0; ni < 4; ++ni){
        int d = ni * 16 + li;                  // 0..63 within head
        float bb = bias[bn * 128 + wc * 64 + d];
#pragma unroll
        for (int mi = 0; mi < 4; ++mi){
#pragma unroll
            for (int r = 0; r < 4; ++r){
                int row = arow0 + wr * 64 + mi * 16 + g * 4 + r;  // global b*T+t
                int b_ = row >> 11, t = row & 2047;
                float val = (acc[mi][ni][r] + bb) * mul;
                dst[(((size_t)(b_ * NH + h)) * SEQ + t) * HD + d] = f2bf(val);
            }
        }
    }
}

// Projection GEMM, fp32 output
__global__ __launch_bounds__(256) void proj_gemm(const short* __restrict__ A,
                                                 const short* __restrict__ Bt,
                                                 const float* __restrict__ bias,
                                                 float* __restrict__ out){
    __shared__ __align__(16) short As[2][BM * BK];
    __shared__ __align__(16) short Bs[2][BM * BK];
    const int tid = threadIdx.x;
    const int bn = blockIdx.x, bm = blockIdx.y;
    const int lane = tid & 63, wid = tid >> 6;
    const int wr = wid >> 1, wc = wid & 1;
    const int li = lane & 15, g = lane >> 4;
    const int arow0 = bm * BM, brow0 = bn * BN;

    f32x4 acc[4][4];
#pragma unroll
    for (int i = 0; i < 4; ++i)
#pragma unroll
        for (int j = 0; j < 4; ++j) acc[i][j] = f32x4{0.f,0.f,0.f,0.f};

    auto stage = [&](int buf, int kt){
        const short* ga = A  + (size_t)arow0 * KDIM + kt * BK;
        const short* gb = Bt + (size_t)brow0 * KDIM + kt * BK;
#pragma unroll
        for (int h = 0; h < 2; ++h){
            int f = h * 256 + tid;
            int row = f >> 2, kc = (f & 3) << 3;
            async_copy16(ga + (size_t)row * KDIM + kc, &As[buf][f << 3]);
            async_copy16(gb + (size_t)row * KDIM + kc, &Bs[buf][f << 3]);
        }
    };

    stage(0, 0);
    __syncthreads();
    int buf = 0;
    const int KT = KDIM / BK;
    for (int kt = 0; kt < KT; ++kt){
        if (kt + 1 < KT) stage(buf ^ 1, kt + 1);
        bf16x8 af[4], bfr[4];
#pragma unroll
        for (int mi = 0; mi < 4; ++mi)
            af[mi] = *(const bf16x8*)(&As[buf][(wr*64 + mi*16 + li) * BK + g*8]);
#pragma unroll
        for (int ni = 0; ni < 4; ++ni)
            bfr[ni] = *(const bf16x8*)(&Bs[buf][(wc*64 + ni*16 + li) * BK + g*8]);
#pragma unroll
        for (int mi = 0; mi < 4; ++mi)
#pragma unroll
            for (int ni = 0; ni < 4; ++ni)
                acc[mi][ni] = MFMA16(af[mi], bfr[ni], acc[mi][ni]);
        __syncthreads();
        buf ^= 1;
    }

#pragma unroll
    for (int ni = 0; ni < 4; ++ni){
        int c = brow0 + wc * 64 + ni * 16 + li;
        float bb = bias[c];
#pragma unroll
        for (int mi = 0; mi < 4; ++mi){
#pragma unroll
            for (int r = 0; r < 4; ++r){
                int row = arow0 + wr * 64 + mi * 16 + g * 4 + r;
                out[(size_t)row * CDIM + c] = acc[mi][ni][r] + bb;
            }
        }
    }
}

// ---------- 4) v [B,H,T,64] -> vt [B,H,64,T] ----------
__global__ __launch_bounds__(256) void vtrans(const short* __restrict__ v,
                                              short* __restrict__ vt){
    __shared__ __align__(16) short lds[64 * 80];
    int tid = threadIdx.x;
    int t0 = blockIdx.x * 64;
    int bh = blockIdx.y;
    const short* src = v + ((size_t)bh * SEQ + t0) * HD;
#pragma unroll
    for (int it = 0; it < 2; ++it){
        int idx = it * 256 + tid;
        int r = idx >> 3, c8 = (idx & 7) << 3;
        *(bf16x8*)(&lds[r * 80 + c8]) = *(const bf16x8*)(src + (size_t)r * HD + c8);
    }
    __syncthreads();
    short* dst = vt + (size_t)bh * HD * SEQ + t0;
#pragma unroll
    for (int it = 0; it < 2; ++it){
        int idx = it * 256 + tid;
        int dl = idx >> 3, t8 = (idx & 7) << 3;
        short4v o0, o1;
#pragma unroll
        for (int j = 0; j < 4; ++j){
            o0[j] = lds[(t8 + j) * 80 + dl];
            o1[j] = lds[(t8 + 4 + j) * 80 + dl];
        }
        short4v* d = (short4v*)(dst + (size_t)dl * SEQ + t8);
        d[0] = o0; d[1] = o1;
    }
}

// ---------- 5) flash attention, swapped-QK^T, LDS-staged K/V double buffer ----
// Round-7 deltas vs round-6 (attn only):
//  - v_cvt_pk_bf16_f32 pairs for P-pack and y-pack (was 3-op f2bf per value)
//  - defer-max: skip alpha/rescale while pm - m <= 8 (P bounded by e^8)
//  - s_setprio(1) around the two 8-MFMA clusters
__global__ __launch_bounds__(256) void attn_kernel(const short* __restrict__ q,
                                                   const short* __restrict__ kk,
                                                   const short* __restrict__ vt,
                                                   short* __restrict__ y){
    __shared__ __align__(16) char kvs[2][2][8192];   // [buf][K=0/V=1][64*128B]
    __shared__ __align__(16) char psm[4 * 2048];     // per-wave [16][64] bf16, swizzled
    const int tid = threadIdx.x;
    const int qt = 31 - blockIdx.x;  // longest blocks dispatch first
    const int bh = blockIdx.y;       // 0..63
    const int lane = tid & 63, wid = tid >> 6;
    const int li = lane & 15, g = lane >> 4;
    const int iglob = qt * 64 + wid * 16 + li;       // this lane's q row

    const short* qp = q + ((size_t)bh * SEQ + iglob) * HD;
    bf16x8 qf0 = *(const bf16x8*)(qp + g * 8);
    bf16x8 qf1 = *(const bf16x8*)(qp + 32 + g * 8);

    char* pbase = psm + wid * 2048 + li * 128;
    const int sw = (li & 7) << 4;

    f32x4 acc[4];
#pragma unroll
    for (int df = 0; df < 4; ++df) acc[df] = f32x4{0.f,0.f,0.f,0.f};
    float m = -3e38f, l = 0.f;

    const short* kbp = kk + (size_t)bh * SEQ * HD;
    const short* vbp = vt + (size_t)bh * HD * SEQ;

    // staging: 512 16B-chunks per tile; chunk c -> row r=c>>3, lds seg s=c&7,
    // global seg s^(r&7). Wave w call j covers chunks [(w*2+j)*64, +64).
    const int c0 = (wid * 2) * 64 + lane;        // chunk for j=0
    const int r0 = c0 >> 3, sg0 = (c0 & 7) ^ (r0 & 7);
    const int c1 = c0 + 64;                      // chunk for j=1
    const int r1 = c1 >> 3, sg1 = (c1 & 7) ^ (r1 & 7);

    auto stage = [&](int b, int kt2){
        const int kb2 = kt2 * 64;
        const short* kg = kbp + (size_t)kb2 * HD;
        const short* vg = vbp + kb2;
        char* kd = kvs[b][0];
        char* vd = kvs[b][1];
        async_copy16(kg + r0 * HD + sg0 * 8, kd + c0 * 16);
        async_copy16(kg + r1 * HD + sg1 * 8, kd + c1 * 16);
        async_copy16(vg + (size_t)r0 * SEQ + sg0 * 8, vd + c0 * 16);
        async_copy16(vg + (size_t)r1 * SEQ + sg1 * 8, vd + c1 * 16);
    };

    stage(0, 0);
    asm volatile("s_waitcnt vmcnt(0)" ::: "memory");
    __builtin_amdgcn_s_barrier();
    int buf = 0;
    for (int kt = 0; kt <= qt; ++kt){
        const int kb = kt * 64;
        if (kt < qt) stage(buf ^ 1, kt + 1);

        const char* Kb = kvs[buf][0];
        const char* Vb = kvs[buf][1];

        f32x4 st[4];
#pragma unroll
        for (int kf = 0; kf < 4; ++kf) st[kf] = f32x4{0.f,0.f,0.f,0.f};
        __builtin_amdgcn_s_setprio(1);
#pragma unroll
        for (int kf = 0; kf < 4; ++kf){
            int r = kf * 16 + li;
            bf16x8 k0 = *(const bf16x8*)(Kb + r * 128 + ((g ^ (r & 7)) << 4));
            bf16x8 k1 = *(const bf16x8*)(Kb + r * 128 + (((g + 4) ^ (r & 7)) << 4));
            st[kf] = MFMA16(k0, qf0, st[kf]);
            st[kf] = MFMA16(k1, qf1, st[kf]);
        }
        __builtin_amdgcn_s_setprio(0);
        if (kt == qt){
#pragma unroll
            for (int kf = 0; kf < 4; ++kf)
#pragma unroll
                for (int r = 0; r < 4; ++r)
                    if (kb + kf * 16 + g * 4 + r > iglob) st[kf][r] = -3e38f;
        }
        // softmax (per q-row = per lane after g-reduction)
        float pm = -3e38f;
#pragma unroll
        for (int kf = 0; kf < 4; ++kf)
#pragma unroll
            for (int r = 0; r < 4; ++r) pm = fmaxf(pm, st[kf][r]);
        pm = fmaxf(pm, __shfl_xor(pm, 16, 64));
        pm = fmaxf(pm, __shfl_xor(pm, 32, 64));
        // defer-max: only rescale when the running max is stale by > THR
        if (!__all(pm - m <= DEFER_THR)){
            float mnew = fmaxf(m, pm);
            float alpha = __builtin_amdgcn_exp2f((m - mnew) * L2E);
            l *= alpha;
#pragma unroll
            for (int df = 0; df < 4; ++df) acc[df] *= alpha;
            m = mnew;
        }
        const float nmL = -m * L2E;
        float rs = 0.f;
#pragma unroll
        for (int kf = 0; kf < 4; ++kf){
            float p0 = __builtin_amdgcn_exp2f(__builtin_fmaf(st[kf][0], L2E, nmL));
            float p1 = __builtin_amdgcn_exp2f(__builtin_fmaf(st[kf][1], L2E, nmL));
            float p2 = __builtin_amdgcn_exp2f(__builtin_fmaf(st[kf][2], L2E, nmL));
            float p3 = __builtin_amdgcn_exp2f(__builtin_fmaf(st[kf][3], L2E, nmL));
            rs += (p0 + p1) + (p2 + p3);
            uint2v pk = { cvtpk(p0, p1), cvtpk(p2, p3) };
            *(uint2v*)(pbase + (((kf << 5) + (g << 3)) ^ sw)) = pk;
        }
        rs += __shfl_xor(rs, 16, 64);
        rs += __shfl_xor(rs, 32, 64);
        l += rs;

        bf16x8 pb0 = *(const bf16x8*)(pbase + (((g << 4)) ^ sw));
        bf16x8 pb1 = *(const bf16x8*)(pbase + ((64 + (g << 4)) ^ sw));
        __builtin_amdgcn_s_setprio(1);
#pragma unroll
        for (int df = 0; df < 4; ++df){
            int d = df * 16 + li;
            bf16x8 v0 = *(const bf16x8*)(Vb + d * 128 + ((g ^ (d & 7)) << 4));
            bf16x8 v1 = *(const bf16x8*)(Vb + d * 128 + (((g + 4) ^ (d & 7)) << 4));
            acc[df] = MFMA16(v0, pb0, acc[df]);
            acc[df] = MFMA16(v1, pb1, acc[df]);
        }
        __builtin_amdgcn_s_setprio(0);

        asm volatile("s_waitcnt vmcnt(0)" ::: "memory");  // next tile resident
        __builtin_amdgcn_s_barrier();                     // all waves done w/ buf
        buf ^= 1;
    }

    float rl = 1.f / l;
    const int b_ = bh >> 4, h = bh & 15;
    short* yp = y + ((size_t)(b_ * SEQ + iglob)) * CDIM + h * HD;
#pragma unroll
    for (int df = 0; df < 4; ++df){
        uint2v o = { cvtpk(acc[df][0] * rl, acc[df][1] * rl),
                     cvtpk(acc[df][2] * rl, acc[df][3] * rl) };
        *(uint2v*)(yp + df * 16 + g * 4) = o;
    }
}

// ---------- launch ----------
extern "C" void kernel_launch(void* const* d_in, const int* in_sizes, int n_in,
                              void* d_out, int out_size, void* d_ws, size_t ws_size,
                              hipStream_t stream){
    const float* x      = (const float*)d_in[0];
    const float* W_attn = (const float*)d_in[1];
    const float* b_attn = (const float*)d_in[2];
    const float* W_proj = (const float*)d_in[3];
    const float* b_proj = (const float*)d_in[4];
    float* out = (float*)d_out;

    // Workspace layout (92,274,688 B total). y aliases xb (xb dead after qkv_gemm).
    if (ws_size < (size_t)92274688) return;  // avoid OOB writes -> clean failure

    char* ws = (char*)d_ws;
    short* Wtp = (short*)(ws);
    short* q   = (short*)(ws + 2097152);
    short* kk  = (short*)(ws + 18874368);
    short* v   = (short*)(ws + 35651584);
    short* vt  = (short*)(ws + 52428800);
    short* xb  = (short*)(ws + 69206016);
    short* y   = xb;
    short* Wta = (short*)(ws + 85983232);

    cvt_x <<<4096, 256, 0, stream>>>(x, xb);
    wtrans<<<dim3(48, 16), 256, 0, stream>>>(W_attn, Wta, 1024, 3072);
    wtrans<<<dim3(16, 16), 256, 0, stream>>>(W_proj, Wtp, 1024, 1024);
    qkv_gemm<<<dim3(24, 64), 256, 0, stream>>>(xb, Wta, b_attn, q, kk, v);
    vtrans<<<dim3(32, 64), 256, 0, stream>>>(v, vt);
    attn_kernel<<<dim3(32, 64), 256, 0, stream>>>(q, kk, vt, y);
    proj_gemm<<<dim3(8, 64), 256, 0, stream>>>(y, Wtp, b_proj, out);
}

// Round 9
// 317.616 us; speedup vs baseline: 2.0353x; 1.0241x over previous
//
#include <hip/hip_runtime.h>

// ---------- types ----------
typedef __attribute__((ext_vector_type(8))) __bf16 bf16x8;   // MFMA A/B operand (4 VGPR)
typedef __attribute__((ext_vector_type(4))) float  f32x4;    // MFMA C/D operand
typedef __attribute__((ext_vector_type(4))) short  short4v;  // 8B packed bf16 store
typedef __attribute__((ext_vector_type(4))) float  float4v;
typedef __attribute__((ext_vector_type(2))) unsigned int uint2v;

#define MFMA16(a,b,c) __builtin_amdgcn_mfma_f32_16x16x32_bf16((a),(b),(c),0,0,0)

// fp32 -> bf16 bits, round-to-nearest-even (finite inputs only)
__device__ __forceinline__ short f2bf(float f){
    unsigned int u = __builtin_bit_cast(unsigned int, f);
    u += 0x7fffu + ((u >> 16) & 1u);
    return (short)(u >> 16);
}

// pack two f32 -> one dword of 2 bf16 (RNE), single HW instruction
__device__ __forceinline__ unsigned int cvtpk(float a, float b){
    unsigned int w;
    asm("v_cvt_pk_bf16_f32 %0, %1, %2" : "=v"(w) : "v"(a), "v"(b));
    return w;
}

typedef __attribute__((address_space(1))) void gvoid;
typedef __attribute__((address_space(3))) void lvoid;
__device__ __forceinline__ void async_copy16(const void* g, void* l){
    __builtin_amdgcn_global_load_lds(
        (gvoid*)(unsigned long long)g,
        (lvoid*)(unsigned int)(unsigned long long)l,
        16, 0, 0);
}

// ---------- problem constants ----------
#define BATCH 4
#define SEQ   2048
#define CDIM  1024
#define NH    16
#define HD    64
#define BT    8192          // BATCH*SEQ
#define QSCALE 0.0125f      // 0.1 / sqrt(64)
#define L2E 1.44269504088896340736f
#define DEFER_THR 8.0f      // skip O/l rescale while pm - m <= THR (P <= e^8)

// ---------- 1) fp32 -> bf16 elementwise (x) ----------
__global__ __launch_bounds__(256) void cvt_x(const float* __restrict__ x,
                                             short* __restrict__ xb){
    int idx = blockIdx.x * 256 + threadIdx.x;      // 8 elems / thread, exact cover
    const float* s = x + (size_t)idx * 8;
    float4v a = *(const float4v*)(s);
    float4v b = *(const float4v*)(s + 4);
    short4v lo, hi;
#pragma unroll
    for (int j = 0; j < 4; ++j){ lo[j] = f2bf(a[j]); hi[j] = f2bf(b[j]); }
    short4v* d = (short4v*)(xb + (size_t)idx * 8);
    d[0] = lo; d[1] = hi;
}

// ---------- 2) fp32 W[K][N] -> bf16 Wt[N][K] (transpose-convert) ----------
__global__ __launch_bounds__(256) void wtrans(const float* __restrict__ W,
                                              short* __restrict__ Wt,
                                              int K, int N){
    __shared__ __align__(16) short lds[64 * 80];
    int tid = threadIdx.x;
    int n0 = blockIdx.x * 64, k0 = blockIdx.y * 64;
#pragma unroll
    for (int it = 0; it < 4; ++it){
        int idx = it * 256 + tid;
        int r = idx >> 4, c4 = (idx & 15) << 2;
        float4v w = *(const float4v*)(W + (size_t)(k0 + r) * N + n0 + c4);
        short4v h4;
#pragma unroll
        for (int j = 0; j < 4; ++j) h4[j] = f2bf(w[j]);
        *(short4v*)(&lds[r * 80 + c4]) = h4;
    }
    __syncthreads();
#pragma unroll
    for (int it = 0; it < 2; ++it){
        int idx = it * 256 + tid;
        int nl = idx >> 3, k8 = (idx & 7) << 3;
        short4v o0, o1;
#pragma unroll
        for (int j = 0; j < 4; ++j){
            o0[j] = lds[(k8 + j) * 80 + nl];
            o1[j] = lds[(k8 + 4 + j) * 80 + nl];
        }
        short4v* d = (short4v*)(Wt + (size_t)(n0 + nl) * K + k0 + k8);
        d[0] = o0; d[1] = o1;
    }
}

// ---------- 3) GEMM core: C[M][*] = A[M][1024] * Bt[N][1024]^T ----------
#define BM 128
#define BN 128
#define BK 32
#define KDIM 1024

// QKV GEMM with scatter epilogue into q/k/v [B,H,T,64] (q pre-scaled)
__global__ __launch_bounds__(256) void qkv_gemm(const short* __restrict__ A,
                                                const short* __restrict__ Bt,
                                                const float* __restrict__ bias,
                                                short* __restrict__ q,
                                                short* __restrict__ k,
                                                short* __restrict__ v){
    __shared__ __align__(16) short As[2][BM * BK];
    __shared__ __align__(16) short Bs[2][BM * BK];
    const int tid = threadIdx.x;
    const int bn = blockIdx.x, bm = blockIdx.y;
    const int lane = tid & 63, wid = tid >> 6;
    const int wr = wid >> 1, wc = wid & 1;
    const int li = lane & 15, g = lane >> 4;
    const int arow0 = bm * BM, brow0 = bn * BN;

    f32x4 acc[4][4];
#pragma unroll
    for (int i = 0; i < 4; ++i)
#pragma unroll
        for (int j = 0; j < 4; ++j) acc[i][j] = f32x4{0.f,0.f,0.f,0.f};

    auto stage = [&](int buf, int kt){
        const short* ga = A  + (size_t)arow0 * KDIM + kt * BK;
        const short* gb = Bt + (size_t)brow0 * KDIM + kt * BK;
#pragma unroll
        for (int h = 0; h < 2; ++h){
            int f = h * 256 + tid;
            int row = f >> 2, kc = (f & 3) << 3;
            async_copy16(ga + (size_t)row * KDIM + kc, &As[buf][f << 3]);
            async_copy16(gb + (size_t)row * KDIM + kc, &Bs[buf][f << 3]);
        }
    };

    stage(0, 0);
    __syncthreads();
    int buf = 0;
    const int KT = KDIM / BK;
    for (int kt = 0; kt < KT; ++kt){
        if (kt + 1 < KT) stage(buf ^ 1, kt + 1);
        bf16x8 af[4], bfr[4];
#pragma unroll
        for (int mi = 0; mi < 4; ++mi)
            af[mi] = *(const bf16x8*)(&As[buf][(wr*64 + mi*16 + li) * BK + g*8]);
#pragma unroll
        for (int ni = 0; ni < 4; ++ni)
            bfr[ni] = *(const bf16x8*)(&Bs[buf][(wc*64 + ni*16 + li) * BK + g*8]);
#pragma unroll
        for (int mi = 0; mi < 4; ++mi)
#pragma unroll
            for (int ni = 0; ni < 4; ++ni)
                acc[mi][ni] = MFMA16(af[mi], bfr[ni], acc[mi][ni]);
        __syncthreads();
        buf ^= 1;
    }

    // epilogue: section (q/k/v) and head are uniform per wave
    const int sec = bn >> 3;                    // 0:q 1:k 2:v
    const int h   = ((bn & 7) << 1) | wc;      // head
    short* dst = (sec == 0) ? q : ((sec == 1) ? k : v);
    const float mul = (sec == 0) ? QSCALE : 1.0f;
#pragma unroll
    for (int ni = 0; ni < 4; ++ni){
        int d = ni * 16 + li;                  // 0..63 within head
        float bb = bias[bn * 128 + wc * 64 + d];
#pragma unroll
        for (int mi = 0; mi < 4; ++mi){
#pragma unroll
            for (int r = 0; r < 4; ++r){
                int row = arow0 + wr * 64 + mi * 16 + g * 4 + r;  // global b*T+t
                int b_ = row >> 11, t = row & 2047;
                float val = (acc[mi][ni][r] + bb) * mul;
                dst[(((size_t)(b_ * NH + h)) * SEQ + t) * HD + d] = f2bf(val);
            }
        }
    }
}

// Projection GEMM, fp32 output
__global__ __launch_bounds__(256) void proj_gemm(const short* __restrict__ A,
                                                 const short* __restrict__ Bt,
                                                 const float* __restrict__ bias,
                                                 float* __restrict__ out){
    __shared__ __align__(16) short As[2][BM * BK];
    __shared__ __align__(16) short Bs[2][BM * BK];
    const int tid = threadIdx.x;
    const int bn = blockIdx.x, bm = blockIdx.y;
    const int lane = tid & 63, wid = tid >> 6;
    const int wr = wid >> 1, wc = wid & 1;
    const int li = lane & 15, g = lane >> 4;
    const int arow0 = bm * BM, brow0 = bn * BN;

    f32x4 acc[4][4];
#pragma unroll
    for (int i = 0; i < 4; ++i)
#pragma unroll
        for (int j = 0; j < 4; ++j) acc[i][j] = f32x4{0.f,0.f,0.f,0.f};

    auto stage = [&](int buf, int kt){
        const short* ga = A  + (size_t)arow0 * KDIM + kt * BK;
        const short* gb = Bt + (size_t)brow0 * KDIM + kt * BK;
#pragma unroll
        for (int h = 0; h < 2; ++h){
            int f = h * 256 + tid;
            int row = f >> 2, kc = (f & 3) << 3;
            async_copy16(ga + (size_t)row * KDIM + kc, &As[buf][f << 3]);
            async_copy16(gb + (size_t)row * KDIM + kc, &Bs[buf][f << 3]);
        }
    };

    stage(0, 0);
    __syncthreads();
    int buf = 0;
    const int KT = KDIM / BK;
    for (int kt = 0; kt < KT; ++kt){
        if (kt + 1 < KT) stage(buf ^ 1, kt + 1);
        bf16x8 af[4], bfr[4];
#pragma unroll
        for (int mi = 0; mi < 4; ++mi)
            af[mi] = *(const bf16x8*)(&As[buf][(wr*64 + mi*16 + li) * BK + g*8]);
#pragma unroll
        for (int ni = 0; ni < 4; ++ni)
            bfr[ni] = *(const bf16x8*)(&Bs[buf][(wc*64 + ni*16 + li) * BK + g*8]);
#pragma unroll
        for (int mi = 0; mi < 4; ++mi)
#pragma unroll
            for (int ni = 0; ni < 4; ++ni)
                acc[mi][ni] = MFMA16(af[mi], bfr[ni], acc[mi][ni]);
        __syncthreads();
        buf ^= 1;
    }

#pragma unroll
    for (int ni = 0; ni < 4; ++ni){
        int c = brow0 + wc * 64 + ni * 16 + li;
        float bb = bias[c];
#pragma unroll
        for (int mi = 0; mi < 4; ++mi){
#pragma unroll
            for (int r = 0; r < 4; ++r){
                int row = arow0 + wr * 64 + mi * 16 + g * 4 + r;
                out[(size_t)row * CDIM + c] = acc[mi][ni][r] + bb;
            }
        }
    }
}

// ---------- 4) v [B,H,T,64] -> vt [B,H,64,T] ----------
__global__ __launch_bounds__(256) void vtrans(const short* __restrict__ v,
                                              short* __restrict__ vt){
    __shared__ __align__(16) short lds[64 * 80];
    int tid = threadIdx.x;
    int t0 = blockIdx.x * 64;
    int bh = blockIdx.y;
    const short* src = v + ((size_t)bh * SEQ + t0) * HD;
#pragma unroll
    for (int it = 0; it < 2; ++it){
        int idx = it * 256 + tid;
        int r = idx >> 3, c8 = (idx & 7) << 3;
        *(bf16x8*)(&lds[r * 80 + c8]) = *(const bf16x8*)(src + (size_t)r * HD + c8);
    }
    __syncthreads();
    short* dst = vt + (size_t)bh * HD * SEQ + t0;
#pragma unroll
    for (int it = 0; it < 2; ++it){
        int idx = it * 256 + tid;
        int dl = idx >> 3, t8 = (idx & 7) << 3;
        short4v o0, o1;
#pragma unroll
        for (int j = 0; j < 4; ++j){
            o0[j] = lds[(t8 + j) * 80 + dl];
            o1[j] = lds[(t8 + 4 + j) * 80 + dl];
        }
        short4v* d = (short4v*)(dst + (size_t)dl * SEQ + t8);
        d[0] = o0; d[1] = o1;
    }
}

// ---------- 5) flash attention, QBLK=128 (2 q-frags/wave), KVBLK=64 ----------
// Round-9 delta: each wave owns q-rows ig0=qt*128+wid*16+li and ig1=ig0+64.
// Per K/V tile: 32 MFMA/wave (was 16); K and V LDS reads SHARED across frags;
// staging bytes, barriers per q-row halved. Causal tail handled by per-frag
// masks (frag0 fully masked on the last tile -> contributes 0, defer-max skips).
__global__ __launch_bounds__(256) void attn_kernel(const short* __restrict__ q,
                                                   const short* __restrict__ kk,
                                                   const short* __restrict__ vt,
                                                   short* __restrict__ y){
    __shared__ __align__(16) char kvs[2][2][8192];   // [buf][K=0/V=1][64*128B]
    __shared__ __align__(16) char psm[4][2][2048];   // [wave][frag][16 q x 64 k bf16]
    const int tid = threadIdx.x;
    const int qt = 15 - blockIdx.x;  // longest blocks dispatch first
    const int bh = blockIdx.y;       // 0..63
    const int lane = tid & 63, wid = tid >> 6;
    const int li = lane & 15, g = lane >> 4;
    const int ig0 = qt * 128 + wid * 16 + li;        // frag0 q row
    const int ig1 = ig0 + 64;                        // frag1 q row

    const short* qpA = q + ((size_t)bh * SEQ + ig0) * HD;
    const short* qpB = q + ((size_t)bh * SEQ + ig1) * HD;
    bf16x8 qA0 = *(const bf16x8*)(qpA + g * 8);
    bf16x8 qA1 = *(const bf16x8*)(qpA + 32 + g * 8);
    bf16x8 qB0 = *(const bf16x8*)(qpB + g * 8);
    bf16x8 qB1 = *(const bf16x8*)(qpB + 32 + g * 8);

    char* p0w = psm[wid][0] + li * 128;
    char* p1w = psm[wid][1] + li * 128;
    const int sw = (li & 7) << 4;

    f32x4 acc0[4], acc1[4];
#pragma unroll
    for (int df = 0; df < 4; ++df){
        acc0[df] = f32x4{0.f,0.f,0.f,0.f};
        acc1[df] = f32x4{0.f,0.f,0.f,0.f};
    }
    float m0 = -3e38f, l0 = 0.f, m1 = -3e38f, l1 = 0.f;

    const short* kbp = kk + (size_t)bh * SEQ * HD;
    const short* vbp = vt + (size_t)bh * HD * SEQ;

    // staging: 512 16B-chunks per tile; chunk c -> row r=c>>3, lds seg s=c&7,
    // global seg s^(r&7). Wave w call j covers chunks [(w*2+j)*64, +64).
    const int c0 = (wid * 2) * 64 + lane;
    const int r0 = c0 >> 3, sg0 = (c0 & 7) ^ (r0 & 7);
    const int c1 = c0 + 64;
    const int r1 = c1 >> 3, sg1 = (c1 & 7) ^ (r1 & 7);

    auto stage = [&](int b, int kt2){
        const int kb2 = kt2 * 64;
        const short* kg = kbp + (size_t)kb2 * HD;
        const short* vg = vbp + kb2;
        char* kd = kvs[b][0];
        char* vd = kvs[b][1];
        async_copy16(kg + r0 * HD + sg0 * 8, kd + c0 * 16);
        async_copy16(kg + r1 * HD + sg1 * 8, kd + c1 * 16);
        async_copy16(vg + (size_t)r0 * SEQ + sg0 * 8, vd + c0 * 16);
        async_copy16(vg + (size_t)r1 * SEQ + sg1 * 8, vd + c1 * 16);
    };

    const int NT = 2 * qt + 2;
    stage(0, 0);
    asm volatile("s_waitcnt vmcnt(0)" ::: "memory");
    __builtin_amdgcn_s_barrier();
    int buf = 0;
    for (int kt = 0; kt < NT; ++kt){
        const int kb = kt * 64;
        if (kt + 1 < NT) stage(buf ^ 1, kt + 1);

        const char* Kb = kvs[buf][0];
        const char* Vb = kvs[buf][1];

        f32x4 st0[4], st1[4];
#pragma unroll
        for (int kf = 0; kf < 4; ++kf){
            st0[kf] = f32x4{0.f,0.f,0.f,0.f};
            st1[kf] = f32x4{0.f,0.f,0.f,0.f};
        }
        __builtin_amdgcn_s_setprio(1);
#pragma unroll
        for (int kf = 0; kf < 4; ++kf){
            int r = kf * 16 + li;
            bf16x8 k0 = *(const bf16x8*)(Kb + r * 128 + ((g ^ (r & 7)) << 4));
            bf16x8 k1 = *(const bf16x8*)(Kb + r * 128 + (((g + 4) ^ (r & 7)) << 4));
            st0[kf] = MFMA16(k0, qA0, st0[kf]);
            st0[kf] = MFMA16(k1, qA1, st0[kf]);
            st1[kf] = MFMA16(k0, qB0, st1[kf]);
            st1[kf] = MFMA16(k1, qB1, st1[kf]);
        }
        __builtin_amdgcn_s_setprio(0);
        if (kt >= 2 * qt){
#pragma unroll
            for (int kf = 0; kf < 4; ++kf)
#pragma unroll
                for (int r = 0; r < 4; ++r)
                    if (kb + kf * 16 + g * 4 + r > ig0) st0[kf][r] = -3e38f;
            if (kt == 2 * qt + 1){
#pragma unroll
                for (int kf = 0; kf < 4; ++kf)
#pragma unroll
                    for (int r = 0; r < 4; ++r)
                        if (kb + kf * 16 + g * 4 + r > ig1) st1[kf][r] = -3e38f;
            }
        }
        // per-frag row max (per lane after g-reduction)
        float pm0 = -3e38f, pm1 = -3e38f;
#pragma unroll
        for (int kf = 0; kf < 4; ++kf)
#pragma unroll
            for (int r = 0; r < 4; ++r){
                pm0 = fmaxf(pm0, st0[kf][r]);
                pm1 = fmaxf(pm1, st1[kf][r]);
            }
        pm0 = fmaxf(pm0, __shfl_xor(pm0, 16, 64));
        pm0 = fmaxf(pm0, __shfl_xor(pm0, 32, 64));
        pm1 = fmaxf(pm1, __shfl_xor(pm1, 16, 64));
        pm1 = fmaxf(pm1, __shfl_xor(pm1, 32, 64));
        // defer-max: rescale only when either frag's running max is stale
        if (!__all((pm0 - m0 <= DEFER_THR) && (pm1 - m1 <= DEFER_THR))){
            float mn0 = fmaxf(m0, pm0), mn1 = fmaxf(m1, pm1);
            float a0 = __builtin_amdgcn_exp2f((m0 - mn0) * L2E);
            float a1 = __builtin_amdgcn_exp2f((m1 - mn1) * L2E);
            l0 *= a0; l1 *= a1;
#pragma unroll
            for (int df = 0; df < 4; ++df){ acc0[df] *= a0; acc1[df] *= a1; }
            m0 = mn0; m1 = mn1;
        }
        const float nm0 = -m0 * L2E, nm1 = -m1 * L2E;
        float rs0 = 0.f, rs1 = 0.f;
#pragma unroll
        for (int kf = 0; kf < 4; ++kf){
            float a0 = __builtin_amdgcn_exp2f(__builtin_fmaf(st0[kf][0], L2E, nm0));
            float a1 = __builtin_amdgcn_exp2f(__builtin_fmaf(st0[kf][1], L2E, nm0));
            float a2 = __builtin_amdgcn_exp2f(__builtin_fmaf(st0[kf][2], L2E, nm0));
            float a3 = __builtin_amdgcn_exp2f(__builtin_fmaf(st0[kf][3], L2E, nm0));
            rs0 += (a0 + a1) + (a2 + a3);
            uint2v pk0 = { cvtpk(a0, a1), cvtpk(a2, a3) };
            *(uint2v*)(p0w + (((kf << 5) + (g << 3)) ^ sw)) = pk0;
            float b0 = __builtin_amdgcn_exp2f(__builtin_fmaf(st1[kf][0], L2E, nm1));
            float b1 = __builtin_amdgcn_exp2f(__builtin_fmaf(st1[kf][1], L2E, nm1));
            float b2 = __builtin_amdgcn_exp2f(__builtin_fmaf(st1[kf][2], L2E, nm1));
            float b3 = __builtin_amdgcn_exp2f(__builtin_fmaf(st1[kf][3], L2E, nm1));
            rs1 += (b0 + b1) + (b2 + b3);
            uint2v pk1 = { cvtpk(b0, b1), cvtpk(b2, b3) };
            *(uint2v*)(p1w + (((kf << 5) + (g << 3)) ^ sw)) = pk1;
        }
        rs0 += __shfl_xor(rs0, 16, 64);
        rs1 += __shfl_xor(rs1, 16, 64);
        rs0 += __shfl_xor(rs0, 32, 64);
        rs1 += __shfl_xor(rs1, 32, 64);
        l0 += rs0; l1 += rs1;

        bf16x8 p00 = *(const bf16x8*)(p0w + (((g << 4)) ^ sw));
        bf16x8 p01 = *(const bf16x8*)(p0w + ((64 + (g << 4)) ^ sw));
        bf16x8 p10 = *(const bf16x8*)(p1w + (((g << 4)) ^ sw));
        bf16x8 p11 = *(const bf16x8*)(p1w + ((64 + (g << 4)) ^ sw));
        __builtin_amdgcn_s_setprio(1);
#pragma unroll
        for (int df = 0; df < 4; ++df){
            int d = df * 16 + li;
            bf16x8 v0 = *(const bf16x8*)(Vb + d * 128 + ((g ^ (d & 7)) << 4));
            bf16x8 v1 = *(const bf16x8*)(Vb + d * 128 + (((g + 4) ^ (d & 7)) << 4));
            acc0[df] = MFMA16(v0, p00, acc0[df]);
            acc0[df] = MFMA16(v1, p01, acc0[df]);
            acc1[df] = MFMA16(v0, p10, acc1[df]);
            acc1[df] = MFMA16(v1, p11, acc1[df]);
        }
        __builtin_amdgcn_s_setprio(0);

        asm volatile("s_waitcnt vmcnt(0)" ::: "memory");  // next tile resident
        __builtin_amdgcn_s_barrier();                     // all waves done w/ buf
        buf ^= 1;
    }

    float rl0 = 1.f / l0, rl1 = 1.f / l1;
    const int b_ = bh >> 4, h = bh & 15;
    short* yp0 = y + ((size_t)(b_ * SEQ + ig0)) * CDIM + h * HD;
    short* yp1 = y + ((size_t)(b_ * SEQ + ig1)) * CDIM + h * HD;
#pragma unroll
    for (int df = 0; df < 4; ++df){
        uint2v o0 = { cvtpk(acc0[df][0] * rl0, acc0[df][1] * rl0),
                      cvtpk(acc0[df][2] * rl0, acc0[df][3] * rl0) };
        *(uint2v*)(yp0 + df * 16 + g * 4) = o0;
        uint2v o1 = { cvtpk(acc1[df][0] * rl1, acc1[df][1] * rl1),
                      cvtpk(acc1[df][2] * rl1, acc1[df][3] * rl1) };
        *(uint2v*)(yp1 + df * 16 + g * 4) = o1;
    }
}

// ---------- launch ----------
extern "C" void kernel_launch(void* const* d_in, const int* in_sizes, int n_in,
                              void* d_out, int out_size, void* d_ws, size_t ws_size,
                              hipStream_t stream){
    const float* x      = (const float*)d_in[0];
    const float* W_attn = (const float*)d_in[1];
    const float* b_attn = (const float*)d_in[2];
    const float* W_proj = (const float*)d_in[3];
    const float* b_proj = (const float*)d_in[4];
    float* out = (float*)d_out;

    // Workspace layout (92,274,688 B total). y aliases xb (xb dead after qkv_gemm).
    if (ws_size < (size_t)92274688) return;  // avoid OOB writes -> clean failure

    char* ws = (char*)d_ws;
    short* Wtp = (short*)(ws);
    short* q   = (short*)(ws + 2097152);
    short* kk  = (short*)(ws + 18874368);
    short* v   = (short*)(ws + 35651584);
    short* vt  = (short*)(ws + 52428800);
    short* xb  = (short*)(ws + 69206016);
    short* y   = xb;
    short* Wta = (short*)(ws + 85983232);

    cvt_x <<<4096, 256, 0, stream>>>(x, xb);
    wtrans<<<dim3(48, 16), 256, 0, stream>>>(W_attn, Wta, 1024, 3072);
    wtrans<<<dim3(16, 16), 256, 0, stream>>>(W_proj, Wtp, 1024, 1024);
    qkv_gemm<<<dim3(24, 64), 256, 0, stream>>>(xb, Wta, b_attn, q, kk, v);
    vtrans<<<dim3(32, 64), 256, 0, stream>>>(v, vt);
    attn_kernel<<<dim3(16, 64), 256, 0, stream>>>(q, kk, vt, y);
    proj_gemm<<<dim3(8, 64), 256, 0, stream>>>(y, Wtp, b_proj, out);
}

// Round 10
// 308.162 us; speedup vs baseline: 2.0977x; 1.0307x over previous
//
#include <hip/hip_runtime.h>

// ---------- types ----------
typedef __attribute__((ext_vector_type(8))) __bf16 bf16x8;   // MFMA A/B operand (4 VGPR)
typedef __attribute__((ext_vector_type(4))) float  f32x4;    // MFMA C/D operand
typedef __attribute__((ext_vector_type(4))) short  short4v;  // 8B packed bf16 store
typedef __attribute__((ext_vector_type(4))) float  float4v;
typedef __attribute__((ext_vector_type(2))) unsigned int uint2v;

#define MFMA16(a,b,c) __builtin_amdgcn_mfma_f32_16x16x32_bf16((a),(b),(c),0,0,0)

// fp32 -> bf16 bits, round-to-nearest-even (finite inputs only)
__device__ __forceinline__ short f2bf(float f){
    unsigned int u = __builtin_bit_cast(unsigned int, f);
    u += 0x7fffu + ((u >> 16) & 1u);
    return (short)(u >> 16);
}

// pack two f32 -> one dword of 2 bf16 (RNE), single HW instruction
__device__ __forceinline__ unsigned int cvtpk(float a, float b){
    unsigned int w;
    asm("v_cvt_pk_bf16_f32 %0, %1, %2" : "=v"(w) : "v"(a), "v"(b));
    return w;
}

typedef __attribute__((address_space(1))) void gvoid;
typedef __attribute__((address_space(3))) void lvoid;
__device__ __forceinline__ void async_copy16(const void* g, void* l){
    __builtin_amdgcn_global_load_lds(
        (gvoid*)(unsigned long long)g,
        (lvoid*)(unsigned int)(unsigned long long)l,
        16, 0, 0);
}

// ---------- problem constants ----------
#define BATCH 4
#define SEQ   2048
#define CDIM  1024
#define NH    16
#define HD    64
#define BT    8192          // BATCH*SEQ
#define QSCALE 0.0125f      // 0.1 / sqrt(64)
#define L2E 1.44269504088896340736f
#define DEFER_THR 8.0f      // skip O/l rescale while pm - m <= THR (P <= e^8)

// ---------- 1) fp32 -> bf16 elementwise (x) ----------
__global__ __launch_bounds__(256) void cvt_x(const float* __restrict__ x,
                                             short* __restrict__ xb){
    int idx = blockIdx.x * 256 + threadIdx.x;      // 8 elems / thread, exact cover
    const float* s = x + (size_t)idx * 8;
    float4v a = *(const float4v*)(s);
    float4v b = *(const float4v*)(s + 4);
    short4v lo, hi;
#pragma unroll
    for (int j = 0; j < 4; ++j){ lo[j] = f2bf(a[j]); hi[j] = f2bf(b[j]); }
    short4v* d = (short4v*)(xb + (size_t)idx * 8);
    d[0] = lo; d[1] = hi;
}

// ---------- 2) fp32 W[K][N] -> bf16 Wt[N][K] (transpose-convert) ----------
__global__ __launch_bounds__(256) void wtrans(const float* __restrict__ W,
                                              short* __restrict__ Wt,
                                              int K, int N){
    __shared__ __align__(16) short lds[64 * 80];
    int tid = threadIdx.x;
    int n0 = blockIdx.x * 64, k0 = blockIdx.y * 64;
#pragma unroll
    for (int it = 0; it < 4; ++it){
        int idx = it * 256 + tid;
        int r = idx >> 4, c4 = (idx & 15) << 2;
        float4v w = *(const float4v*)(W + (size_t)(k0 + r) * N + n0 + c4);
        short4v h4;
#pragma unroll
        for (int j = 0; j < 4; ++j) h4[j] = f2bf(w[j]);
        *(short4v*)(&lds[r * 80 + c4]) = h4;
    }
    __syncthreads();
#pragma unroll
    for (int it = 0; it < 2; ++it){
        int idx = it * 256 + tid;
        int nl = idx >> 3, k8 = (idx & 7) << 3;
        short4v o0, o1;
#pragma unroll
        for (int j = 0; j < 4; ++j){
            o0[j] = lds[(k8 + j) * 80 + nl];
            o1[j] = lds[(k8 + 4 + j) * 80 + nl];
        }
        short4v* d = (short4v*)(Wt + (size_t)(n0 + nl) * K + k0 + k8);
        d[0] = o0; d[1] = o1;
    }
}

// ---------- 3) GEMM core: C[M][*] = A[M][1024] * Bt[N][1024]^T ----------
#define BM 128
#define BN 128
#define BK 32
#define KDIM 1024

// QKV GEMM with scatter epilogue into q/k/v [B,H,T,64] (q pre-scaled)
__global__ __launch_bounds__(256) void qkv_gemm(const short* __restrict__ A,
                                                const short* __restrict__ Bt,
                                                const float* __restrict__ bias,
                                                short* __restrict__ q,
                                                short* __restrict__ k,
                                                short* __restrict__ v){
    __shared__ __align__(16) short As[2][BM * BK];
    __shared__ __align__(16) short Bs[2][BM * BK];
    const int tid = threadIdx.x;
    const int bn = blockIdx.x, bm = blockIdx.y;
    const int lane = tid & 63, wid = tid >> 6;
    const int wr = wid >> 1, wc = wid & 1;
    const int li = lane & 15, g = lane >> 4;
    const int arow0 = bm * BM, brow0 = bn * BN;

    f32x4 acc[4][4];
#pragma unroll
    for (int i = 0; i < 4; ++i)
#pragma unroll
        for (int j = 0; j < 4; ++j) acc[i][j] = f32x4{0.f,0.f,0.f,0.f};

    auto stage = [&](int buf, int kt){
        const short* ga = A  + (size_t)arow0 * KDIM + kt * BK;
        const short* gb = Bt + (size_t)brow0 * KDIM + kt * BK;
#pragma unroll
        for (int h = 0; h < 2; ++h){
            int f = h * 256 + tid;
            int row = f >> 2, kc = (f & 3) << 3;
            async_copy16(ga + (size_t)row * KDIM + kc, &As[buf][f << 3]);
            async_copy16(gb + (size_t)row * KDIM + kc, &Bs[buf][f << 3]);
        }
    };

    stage(0, 0);
    __syncthreads();
    int buf = 0;
    const int KT = KDIM / BK;
    for (int kt = 0; kt < KT; ++kt){
        if (kt + 1 < KT) stage(buf ^ 1, kt + 1);
        bf16x8 af[4], bfr[4];
#pragma unroll
        for (int mi = 0; mi < 4; ++mi)
            af[mi] = *(const bf16x8*)(&As[buf][(wr*64 + mi*16 + li) * BK + g*8]);
#pragma unroll
        for (int ni = 0; ni < 4; ++ni)
            bfr[ni] = *(const bf16x8*)(&Bs[buf][(wc*64 + ni*16 + li) * BK + g*8]);
#pragma unroll
        for (int mi = 0; mi < 4; ++mi)
#pragma unroll
            for (int ni = 0; ni < 4; ++ni)
                acc[mi][ni] = MFMA16(af[mi], bfr[ni], acc[mi][ni]);
        __syncthreads();
        buf ^= 1;
    }

    // epilogue: section (q/k/v) and head are uniform per wave
    const int sec = bn >> 3;                    // 0:q 1:k 2:v
    const int h   = ((bn & 7) << 1) | wc;      // head
    short* dst = (sec == 0) ? q : ((sec == 1) ? k : v);
    const float mul = (sec == 0) ? QSCALE : 1.0f;
#pragma unroll
    for (int ni = 0; ni < 4; ++ni){
        int d = ni * 16 + li;                  // 0..63 within head
        float bb = bias[bn * 128 + wc * 64 + d];
#pragma unroll
        for (int mi = 0; mi < 4; ++mi){
#pragma unroll
            for (int r = 0; r < 4; ++r){
                int row = arow0 + wr * 64 + mi * 16 + g * 4 + r;  // global b*T+t
                int b_ = row >> 11, t = row & 2047;
                float val = (acc[mi][ni][r] + bb) * mul;
                dst[(((size_t)(b_ * NH + h)) * SEQ + t) * HD + d] = f2bf(val);
            }
        }
    }
}

// Projection GEMM, fp32 output
__global__ __launch_bounds__(256) void proj_gemm(const short* __restrict__ A,
                                                 const short* __restrict__ Bt,
                                                 const float* __restrict__ bias,
                                                 float* __restrict__ out){
    __shared__ __align__(16) short As[2][BM * BK];
    __shared__ __align__(16) short Bs[2][BM * BK];
    const int tid = threadIdx.x;
    const int bn = blockIdx.x, bm = blockIdx.y;
    const int lane = tid & 63, wid = tid >> 6;
    const int wr = wid >> 1, wc = wid & 1;
    const int li = lane & 15, g = lane >> 4;
    const int arow0 = bm * BM, brow0 = bn * BN;

    f32x4 acc[4][4];
#pragma unroll
    for (int i = 0; i < 4; ++i)
#pragma unroll
        for (int j = 0; j < 4; ++j) acc[i][j] = f32x4{0.f,0.f,0.f,0.f};

    auto stage = [&](int buf, int kt){
        const short* ga = A  + (size_t)arow0 * KDIM + kt * BK;
        const short* gb = Bt + (size_t)brow0 * KDIM + kt * BK;
#pragma unroll
        for (int h = 0; h < 2; ++h){
            int f = h * 256 + tid;
            int row = f >> 2, kc = (f & 3) << 3;
            async_copy16(ga + (size_t)row * KDIM + kc, &As[buf][f << 3]);
            async_copy16(gb + (size_t)row * KDIM + kc, &Bs[buf][f << 3]);
        }
    };

    stage(0, 0);
    __syncthreads();
    int buf = 0;
    const int KT = KDIM / BK;
    for (int kt = 0; kt < KT; ++kt){
        if (kt + 1 < KT) stage(buf ^ 1, kt + 1);
        bf16x8 af[4], bfr[4];
#pragma unroll
        for (int mi = 0; mi < 4; ++mi)
            af[mi] = *(const bf16x8*)(&As[buf][(wr*64 + mi*16 + li) * BK + g*8]);
#pragma unroll
        for (int ni = 0; ni < 4; ++ni)
            bfr[ni] = *(const bf16x8*)(&Bs[buf][(wc*64 + ni*16 + li) * BK + g*8]);
#pragma unroll
        for (int mi = 0; mi < 4; ++mi)
#pragma unroll
            for (int ni = 0; ni < 4; ++ni)
                acc[mi][ni] = MFMA16(af[mi], bfr[ni], acc[mi][ni]);
        __syncthreads();
        buf ^= 1;
    }

#pragma unroll
    for (int ni = 0; ni < 4; ++ni){
        int c = brow0 + wc * 64 + ni * 16 + li;
        float bb = bias[c];
#pragma unroll
        for (int mi = 0; mi < 4; ++mi){
#pragma unroll
            for (int r = 0; r < 4; ++r){
                int row = arow0 + wr * 64 + mi * 16 + g * 4 + r;
                out[(size_t)row * CDIM + c] = acc[mi][ni][r] + bb;
            }
        }
    }
}

// ---------- 4) v [B,H,T,64] -> vt [B,H,64,T] ----------
__global__ __launch_bounds__(256) void vtrans(const short* __restrict__ v,
                                              short* __restrict__ vt){
    __shared__ __align__(16) short lds[64 * 80];
    int tid = threadIdx.x;
    int t0 = blockIdx.x * 64;
    int bh = blockIdx.y;
    const short* src = v + ((size_t)bh * SEQ + t0) * HD;
#pragma unroll
    for (int it = 0; it < 2; ++it){
        int idx = it * 256 + tid;
        int r = idx >> 3, c8 = (idx & 7) << 3;
        *(bf16x8*)(&lds[r * 80 + c8]) = *(const bf16x8*)(src + (size_t)r * HD + c8);
    }
    __syncthreads();
    short* dst = vt + (size_t)bh * HD * SEQ + t0;
#pragma unroll
    for (int it = 0; it < 2; ++it){
        int idx = it * 256 + tid;
        int dl = idx >> 3, t8 = (idx & 7) << 3;
        short4v o0, o1;
#pragma unroll
        for (int j = 0; j < 4; ++j){
            o0[j] = lds[(t8 + j) * 80 + dl];
            o1[j] = lds[(t8 + 4 + j) * 80 + dl];
        }
        short4v* d = (short4v*)(dst + (size_t)dl * SEQ + t8);
        d[0] = o0; d[1] = o1;
    }
}

// ---------- 5) flash attention: 8 waves, QBLK=128, 16 q-rows/wave ----------
// Round-10 delta (vs round 9): keep QBLK=128 traffic geometry, but spread the
// 128 q-rows over 8 waves (512 threads) instead of 2 frags per 4 waves.
// Per wave per tile: 16 MFMA + ONE softmax (round-8 chain length) and only
// 2 staging loads; 24 waves/CU (was 12). LDS 48KB -> 3 blocks/CU.
__global__ __launch_bounds__(512) void attn_kernel(const short* __restrict__ q,
                                                   const short* __restrict__ kk,
                                                   const short* __restrict__ vt,
                                                   short* __restrict__ y){
    __shared__ __align__(16) char kvs[2][2][8192];   // [buf][K=0/V=1][64*128B]
    __shared__ __align__(16) char psm[8][2048];      // per-wave [16 q][64 k] bf16
    const int tid = threadIdx.x;
    const int qt = 15 - blockIdx.x;  // longest blocks dispatch first
    const int bh = blockIdx.y;       // 0..63
    const int lane = tid & 63, wid = tid >> 6;       // wid 0..7
    const int li = lane & 15, g = lane >> 4;
    const int ig = qt * 128 + wid * 16 + li;         // this lane's q row

    const short* qp = q + ((size_t)bh * SEQ + ig) * HD;
    bf16x8 qf0 = *(const bf16x8*)(qp + g * 8);
    bf16x8 qf1 = *(const bf16x8*)(qp + 32 + g * 8);

    char* pbase = psm[wid] + li * 128;
    const int sw = (li & 7) << 4;

    f32x4 acc[4];
#pragma unroll
    for (int df = 0; df < 4; ++df) acc[df] = f32x4{0.f,0.f,0.f,0.f};
    float m = -3e38f, l = 0.f;

    const short* kbp = kk + (size_t)bh * SEQ * HD;
    const short* vbp = vt + (size_t)bh * HD * SEQ;

    // staging: 512 16B-chunks per array (K,V); 8 waves x 64 lanes x 1 chunk each.
    // chunk c -> row r=c>>3, lds seg s=c&7, global seg s^(r&7).
    const int c0 = wid * 64 + lane;
    const int r0 = c0 >> 3, sg0 = (c0 & 7) ^ (r0 & 7);

    auto stage = [&](int b, int kt2){
        const int kb2 = kt2 * 64;
        async_copy16(kbp + ((size_t)(kb2 + r0)) * HD + sg0 * 8, kvs[b][0] + c0 * 16);
        async_copy16(vbp + (size_t)r0 * SEQ + kb2 + sg0 * 8,    kvs[b][1] + c0 * 16);
    };

    const int NT = 2 * qt + 2;
    stage(0, 0);
    asm volatile("s_waitcnt vmcnt(0)" ::: "memory");
    __builtin_amdgcn_s_barrier();
    int buf = 0;
    for (int kt = 0; kt < NT; ++kt){
        const int kb = kt * 64;
        if (kt + 1 < NT) stage(buf ^ 1, kt + 1);

        const char* Kb = kvs[buf][0];
        const char* Vb = kvs[buf][1];

        f32x4 st[4];
#pragma unroll
        for (int kf = 0; kf < 4; ++kf) st[kf] = f32x4{0.f,0.f,0.f,0.f};
        __builtin_amdgcn_s_setprio(1);
#pragma unroll
        for (int kf = 0; kf < 4; ++kf){
            int r = kf * 16 + li;
            bf16x8 k0 = *(const bf16x8*)(Kb + r * 128 + ((g ^ (r & 7)) << 4));
            bf16x8 k1 = *(const bf16x8*)(Kb + r * 128 + (((g + 4) ^ (r & 7)) << 4));
            st[kf] = MFMA16(k0, qf0, st[kf]);
            st[kf] = MFMA16(k1, qf1, st[kf]);
        }
        __builtin_amdgcn_s_setprio(0);
        if (kt >= 2 * qt){
#pragma unroll
            for (int kf = 0; kf < 4; ++kf)
#pragma unroll
                for (int r = 0; r < 4; ++r)
                    if (kb + kf * 16 + g * 4 + r > ig) st[kf][r] = -3e38f;
        }
        // softmax (per q-row = per lane after g-reduction)
        float pm = -3e38f;
#pragma unroll
        for (int kf = 0; kf < 4; ++kf)
#pragma unroll
            for (int r = 0; r < 4; ++r) pm = fmaxf(pm, st[kf][r]);
        pm = fmaxf(pm, __shfl_xor(pm, 16, 64));
        pm = fmaxf(pm, __shfl_xor(pm, 32, 64));
        // defer-max: only rescale when the running max is stale by > THR
        if (!__all(pm - m <= DEFER_THR)){
            float mnew = fmaxf(m, pm);
            float alpha = __builtin_amdgcn_exp2f((m - mnew) * L2E);
            l *= alpha;
#pragma unroll
            for (int df = 0; df < 4; ++df) acc[df] *= alpha;
            m = mnew;
        }
        const float nmL = -m * L2E;
        float rs = 0.f;
#pragma unroll
        for (int kf = 0; kf < 4; ++kf){
            float p0 = __builtin_amdgcn_exp2f(__builtin_fmaf(st[kf][0], L2E, nmL));
            float p1 = __builtin_amdgcn_exp2f(__builtin_fmaf(st[kf][1], L2E, nmL));
            float p2 = __builtin_amdgcn_exp2f(__builtin_fmaf(st[kf][2], L2E, nmL));
            float p3 = __builtin_amdgcn_exp2f(__builtin_fmaf(st[kf][3], L2E, nmL));
            rs += (p0 + p1) + (p2 + p3);
            uint2v pk = { cvtpk(p0, p1), cvtpk(p2, p3) };
            *(uint2v*)(pbase + (((kf << 5) + (g << 3)) ^ sw)) = pk;
        }
        rs += __shfl_xor(rs, 16, 64);
        rs += __shfl_xor(rs, 32, 64);
        l += rs;

        bf16x8 pb0 = *(const bf16x8*)(pbase + (((g << 4)) ^ sw));
        bf16x8 pb1 = *(const bf16x8*)(pbase + ((64 + (g << 4)) ^ sw));
        __builtin_amdgcn_s_setprio(1);
#pragma unroll
        for (int df = 0; df < 4; ++df){
            int d = df * 16 + li;
            bf16x8 v0 = *(const bf16x8*)(Vb + d * 128 + ((g ^ (d & 7)) << 4));
            bf16x8 v1 = *(const bf16x8*)(Vb + d * 128 + (((g + 4) ^ (d & 7)) << 4));
            acc[df] = MFMA16(v0, pb0, acc[df]);
            acc[df] = MFMA16(v1, pb1, acc[df]);
        }
        __builtin_amdgcn_s_setprio(0);

        asm volatile("s_waitcnt vmcnt(0)" ::: "memory");  // next tile resident
        __builtin_amdgcn_s_barrier();                     // all waves done w/ buf
        buf ^= 1;
    }

    float rl = 1.f / l;
    const int b_ = bh >> 4, h = bh & 15;
    short* yp = y + ((size_t)(b_ * SEQ + ig)) * CDIM + h * HD;
#pragma unroll
    for (int df = 0; df < 4; ++df){
        uint2v o = { cvtpk(acc[df][0] * rl, acc[df][1] * rl),
                     cvtpk(acc[df][2] * rl, acc[df][3] * rl) };
        *(uint2v*)(yp + df * 16 + g * 4) = o;
    }
}

// ---------- launch ----------
extern "C" void kernel_launch(void* const* d_in, const int* in_sizes, int n_in,
                              void* d_out, int out_size, void* d_ws, size_t ws_size,
                              hipStream_t stream){
    const float* x      = (const float*)d_in[0];
    const float* W_attn = (const float*)d_in[1];
    const float* b_attn = (const float*)d_in[2];
    const float* W_proj = (const float*)d_in[3];
    const float* b_proj = (const float*)d_in[4];
    float* out = (float*)d_out;

    // Workspace layout (92,274,688 B total). y aliases xb (xb dead after qkv_gemm).
    if (ws_size < (size_t)92274688) return;  // avoid OOB writes -> clean failure

    char* ws = (char*)d_ws;
    short* Wtp = (short*)(ws);
    short* q   = (short*)(ws + 2097152);
    short* kk  = (short*)(ws + 18874368);
    short* v   = (short*)(ws + 35651584);
    short* vt  = (short*)(ws + 52428800);
    short* xb  = (short*)(ws + 69206016);
    short* y   = xb;
    short* Wta = (short*)(ws + 85983232);

    cvt_x <<<4096, 256, 0, stream>>>(x, xb);
    wtrans<<<dim3(48, 16), 256, 0, stream>>>(W_attn, Wta, 1024, 3072);
    wtrans<<<dim3(16, 16), 256, 0, stream>>>(W_proj, Wtp, 1024, 1024);
    qkv_gemm<<<dim3(24, 64), 256, 0, stream>>>(xb, Wta, b_attn, q, kk, v);
    vtrans<<<dim3(32, 64), 256, 0, stream>>>(v, vt);
    attn_kernel<<<dim3(16, 64), 512, 0, stream>>>(q, kk, vt, y);
    proj_gemm<<<dim3(8, 64), 256, 0, stream>>>(y, Wtp, b_proj, out);
}